// Round 2
// baseline (42646.884 us; speedup 1.0000x reference)
//
#include <hip/hip_runtime.h>
#include <math.h>

#define B_  64
#define T_  50
#define S_  50
#define U_  1024
#define E_  100
#define V_  30001
#define U4_ 4096

// ---------------------------------------------------------------------------
// Generic tiled f32 GEMM: C[M,N] = A[M,K] @ B[K,N] (+ bias).  (unchanged)
// ---------------------------------------------------------------------------
__global__ __launch_bounds__(256) void gemm128(
    const float* __restrict__ A, int lda,
    const float* __restrict__ Bm, int ldb,
    float* __restrict__ C, int ldc,
    int N, int K, const float* __restrict__ bias)
{
    __shared__ float As[8][132];
    __shared__ float Bs[8][132];

    const int n0  = blockIdx.x * 128;
    const int m0  = blockIdx.y * 128;
    const int tid = threadIdx.x;
    const int tx  = tid & 15, ty = tid >> 4;

    float acc[8][8];
#pragma unroll
    for (int i = 0; i < 8; ++i)
#pragma unroll
        for (int j = 0; j < 8; ++j) acc[i][j] = 0.f;

    const int ra = tid >> 1, ca = (tid & 1) * 4;
    const int rb = tid >> 5, cb = (tid & 31) * 4;
    const bool fast_b = ((ldb & 3) == 0) && (n0 + 128 <= N);

    for (int k0 = 0; k0 < K; k0 += 8) {
        float4 av = *(const float4*)&A[(size_t)(m0 + ra) * lda + k0 + ca];
        As[ca + 0][ra] = av.x;
        As[ca + 1][ra] = av.y;
        As[ca + 2][ra] = av.z;
        As[ca + 3][ra] = av.w;

        float4 bv;
        if (fast_b) {
            bv = *(const float4*)&Bm[(size_t)(k0 + rb) * ldb + n0 + cb];
        } else {
            const float* bp = &Bm[(size_t)(k0 + rb) * ldb];
            bv.x = (n0 + cb + 0 < N) ? bp[n0 + cb + 0] : 0.f;
            bv.y = (n0 + cb + 1 < N) ? bp[n0 + cb + 1] : 0.f;
            bv.z = (n0 + cb + 2 < N) ? bp[n0 + cb + 2] : 0.f;
            bv.w = (n0 + cb + 3 < N) ? bp[n0 + cb + 3] : 0.f;
        }
        *(float4*)&Bs[rb][cb] = bv;
        __syncthreads();

#pragma unroll
        for (int kk = 0; kk < 8; ++kk) {
            float4 a0 = *(const float4*)&As[kk][ty * 4];
            float4 a1 = *(const float4*)&As[kk][64 + ty * 4];
            float4 b0 = *(const float4*)&Bs[kk][tx * 4];
            float4 b1 = *(const float4*)&Bs[kk][64 + tx * 4];
            float a_[8] = {a0.x, a0.y, a0.z, a0.w, a1.x, a1.y, a1.z, a1.w};
            float b_[8] = {b0.x, b0.y, b0.z, b0.w, b1.x, b1.y, b1.z, b1.w};
#pragma unroll
            for (int i = 0; i < 8; ++i)
#pragma unroll
                for (int j = 0; j < 8; ++j)
                    acc[i][j] = fmaf(a_[i], b_[j], acc[i][j]);
        }
        __syncthreads();
    }

#pragma unroll
    for (int i = 0; i < 8; ++i) {
        int row = m0 + ((i < 4) ? (ty * 4 + i) : (64 + ty * 4 + (i - 4)));
#pragma unroll
        for (int j = 0; j < 8; ++j) {
            int col = n0 + ((j < 4) ? (tx * 4 + j) : (64 + tx * 4 + (j - 4)));
            if (col < N) {
                float v = acc[i][j];
                if (bias) v += bias[col];
                C[(size_t)row * ldc + col] = v;
            }
        }
    }
}

__global__ void add_inplace(float* __restrict__ dst, const float* __restrict__ src, int n)
{
    int i = blockIdx.x * blockDim.x + threadIdx.x;
    if (i < n) dst[i] += src[i];
}

// ---------------------------------------------------------------------------
// Software grid barrier: monotonically increasing counter, agent scope.
// Safe: 256 blocks x 256 threads, <=18KB LDS -> 1 block/CU on 256 CUs,
// all blocks co-resident.
// ---------------------------------------------------------------------------
__device__ __forceinline__ void gbar(unsigned* bar, unsigned& gen)
{
    __syncthreads();
    if (threadIdx.x == 0) {
        gen += gridDim.x;
        __hip_atomic_fetch_add(bar, 1u, __ATOMIC_ACQ_REL, __HIP_MEMORY_SCOPE_AGENT);
        while (__hip_atomic_load(bar, __ATOMIC_ACQUIRE, __HIP_MEMORY_SCOPE_AGENT) < gen)
            __builtin_amdgcn_s_sleep(1);
    }
    __syncthreads();
}

// ---------------------------------------------------------------------------
// Persistent decoder loop: 50 steps, 3 phases/step, software grid barriers.
// grid = 256 blocks x 256 threads.
// Phase A: zp[ks][64][4096] partial GEMM  (block = (nt in 0..31, ks in 0..7),
//          tile 64 rows x 128 cols, K-slice 256, micro 8x4)
// Phase B: gates -> c,h  (block beta: b=beta>>2, u-quarter = beta&3)
// Phase C: scores/softmax/ctx  (blocks 0..63, one per batch)
// ---------------------------------------------------------------------------
__global__ __launch_bounds__(256) void decoder_loop(
    const int*   __restrict__ tokens,
    const float* __restrict__ emb,
    const float* __restrict__ Wx,
    const float* __restrict__ bvec,
    const float* __restrict__ Uh,
    const float* __restrict__ Wcomb,
    const float* __restrict__ keys,
    const float* __restrict__ memory,
    const float* __restrict__ h0,
    const float* __restrict__ c0,
    float* __restrict__ hcprev,   // [64][2048]
    float* __restrict__ cbuf,     // [64][1024]
    float* __restrict__ zp,       // [8][64][4096]
    float* __restrict__ hc_all,   // [64][50][2048]
    unsigned* bar)
{
    __shared__ float As[16][68];    // [k][row]
    __shared__ float Bs[16][132];   // [k][col]
    __shared__ float xe[128];
    __shared__ float hs[1024];
    __shared__ float sc[64];
    __shared__ float al[64];

    const int beta = blockIdx.x;
    const int tid  = threadIdx.x;
    unsigned gen = 0;

    // init: hcprev = [h0 | 0]
    for (int idx = beta * 256 + tid; idx < 64 * 2048; idx += 256 * 256) {
        int row = idx >> 11, col = idx & 2047;
        hcprev[idx] = (col < 1024) ? h0[row * 1024 + col] : 0.f;
    }
    gbar(bar, gen);

    const int nt = beta & 31, ks = beta >> 5;
    const int c0c = nt * 128;
    const int tx = tid & 31, ty = tid >> 5;
    const int arow = tid >> 2, akc = (tid & 3) * 4;
    const int bkb = tid >> 4, bcb = (tid & 15) * 8;
    const int b_B = beta >> 2, q_B = beta & 3, u_B = q_B * 256 + tid;

    for (int t = 0; t < T_; ++t) {
        const int KS = (t == 0) ? 4 : 8;
        // ---------------- phase A: z partials ----------------
        if (ks < KS) {
            const float* Bz = (t == 0) ? Uh : Wcomb;
            const int koff = ks * 256;
            float acc[8][4];
#pragma unroll
            for (int i = 0; i < 8; ++i)
#pragma unroll
                for (int j = 0; j < 4; ++j) acc[i][j] = 0.f;

            for (int kc0 = 0; kc0 < 256; kc0 += 16) {
                float4 av = *(const float4*)&hcprev[arow * 2048 + koff + kc0 + akc];
                As[akc + 0][arow] = av.x;
                As[akc + 1][arow] = av.y;
                As[akc + 2][arow] = av.z;
                As[akc + 3][arow] = av.w;
                const float* brow = &Bz[(size_t)(koff + kc0 + bkb) * U4_ + c0c + bcb];
                *(float4*)&Bs[bkb][bcb]     = *(const float4*)&brow[0];
                *(float4*)&Bs[bkb][bcb + 4] = *(const float4*)&brow[4];
                __syncthreads();
#pragma unroll
                for (int kk = 0; kk < 16; ++kk) {
                    float4 a0 = *(const float4*)&As[kk][ty * 8];
                    float4 a1 = *(const float4*)&As[kk][ty * 8 + 4];
                    float4 bq = *(const float4*)&Bs[kk][tx * 4];
                    float a_[8] = {a0.x, a0.y, a0.z, a0.w, a1.x, a1.y, a1.z, a1.w};
                    float b_[4] = {bq.x, bq.y, bq.z, bq.w};
#pragma unroll
                    for (int i = 0; i < 8; ++i)
#pragma unroll
                        for (int j = 0; j < 4; ++j)
                            acc[i][j] = fmaf(a_[i], b_[j], acc[i][j]);
                }
                __syncthreads();
            }
#pragma unroll
            for (int i = 0; i < 8; ++i) {
                int row = ty * 8 + i;
                *(float4*)&zp[((size_t)ks * 64 + row) * U4_ + c0c + tx * 4] =
                    make_float4(acc[i][0], acc[i][1], acc[i][2], acc[i][3]);
            }
        }
        gbar(bar, gen);

        // ---------------- phase B: gates ----------------
        {
            const int tok = tokens[b_B * T_ + t];
            if (tid < E_) xe[tid] = emb[(size_t)tok * E_ + tid];
            __syncthreads();

            float zg[4];
#pragma unroll
            for (int g = 0; g < 4; ++g) {
                const int col = g * U_ + u_B;
                float a = bvec[col];
                for (int s = 0; s < KS; ++s)
                    a += zp[((size_t)s * 64 + b_B) * U4_ + col];
                float a2 = 0.f;
                for (int e = 0; e < E_; ++e)
                    a2 = fmaf(xe[e], Wx[(size_t)e * U4_ + col], a2);
                zg[g] = a + a2;
            }
            const float si = 1.f / (1.f + expf(-zg[0]));
            const float sf = 1.f / (1.f + expf(-zg[1]));
            const float tg = tanhf(zg[2]);
            const float so = 1.f / (1.f + expf(-zg[3]));
            const float cp = (t == 0) ? c0[b_B * U_ + u_B] : cbuf[b_B * U_ + u_B];
            const float cn = sf * cp + si * tg;
            const float hn = so * tanhf(cn);
            cbuf[b_B * U_ + u_B] = cn;
            hcprev[b_B * 2048 + u_B] = hn;
            hc_all[((size_t)b_B * T_ + t) * 2048 + u_B] = hn;
            __syncthreads();
        }
        gbar(bar, gen);

        // ---------------- phase C: attention ----------------
        if (beta < 64) {
            const int b = beta;
#pragma unroll
            for (int i = 0; i < 4; ++i)
                hs[tid + 256 * i] = hcprev[b * 2048 + tid + 256 * i];
            __syncthreads();

            const int lane = tid & 63, w = tid >> 6;
            for (int s = w; s < S_; s += 4) {
                const float* kp = &keys[((size_t)b * S_ + s) * U_];
                float p = 0.f;
#pragma unroll
                for (int i = 0; i < 16; ++i)
                    p = fmaf(hs[lane + 64 * i], kp[lane + 64 * i], p);
#pragma unroll
                for (int off = 32; off > 0; off >>= 1)
                    p += __shfl_xor(p, off);
                if (lane == 0) sc[s] = p;
            }
            __syncthreads();

            if (tid < 64) {
                float v = (lane < S_) ? sc[lane] : -INFINITY;
                float m = v;
#pragma unroll
                for (int off = 32; off > 0; off >>= 1)
                    m = fmaxf(m, __shfl_xor(m, off));
                float e = (lane < S_) ? expf(v - m) : 0.f;
                float ssum = e;
#pragma unroll
                for (int off = 32; off > 0; off >>= 1)
                    ssum += __shfl_xor(ssum, off);
                if (lane < S_) al[lane] = e / ssum;
            }
            __syncthreads();

#pragma unroll
            for (int i = 0; i < 4; ++i) {
                const int u = tid + 256 * i;
                float cacc = 0.f;
                for (int s = 0; s < S_; ++s)
                    cacc = fmaf(al[s], memory[((size_t)b * S_ + s) * U_ + u], cacc);
                hcprev[b * 2048 + U_ + u] = cacc;
                hc_all[((size_t)b * T_ + t) * 2048 + U_ + u] = cacc;
            }
        }
        gbar(bar, gen);
    }
}

// ---------------------------------------------------------------------------
extern "C" void kernel_launch(void* const* d_in, const int* in_sizes, int n_in,
                              void* d_out, int out_size, void* d_ws, size_t ws_size,
                              hipStream_t stream)
{
    const int*   tokens = (const int*)  d_in[0];
    const float* memory = (const float*)d_in[1];
    const float* h0     = (const float*)d_in[2];
    const float* c0     = (const float*)d_in[3];
    const float* emb    = (const float*)d_in[4];
    const float* Wx     = (const float*)d_in[5];
    const float* Uh     = (const float*)d_in[6];
    const float* bvec   = (const float*)d_in[7];
    const float* Wm     = (const float*)d_in[8];
    const float* Wa     = (const float*)d_in[9];
    const float* Wo     = (const float*)d_in[10];
    const float* bo     = (const float*)d_in[11];
    float* out = (float*)d_out;

    float* ws = (float*)d_ws;
    size_t off = 0;
    float* keys     = ws + off; off += (size_t)B_ * S_ * U_;   // 3,276,800
    float* Wcomb    = ws + off; off += (size_t)2048 * U4_;     // 8,388,608
    float* hc_all   = ws + off; off += (size_t)B_ * T_ * 2048; // 6,553,600
    float* cbuf     = ws + off; off += (size_t)B_ * U_;        //    65,536
    float* zp       = ws + off; off += (size_t)8 * B_ * U4_;   // 2,097,152
    float* hcprev   = ws + off; off += (size_t)B_ * 2048;      //   131,072
    unsigned* bar   = (unsigned*)(ws + off); off += 64;
    float* attn_all = keys;  // keys dead after the loop; alias

    hipMemsetAsync(bar, 0, sizeof(unsigned), stream);

    // 1. Wcomb = Wa @ Wx[E:, :]
    gemm128<<<dim3(32, 16), 256, 0, stream>>>(
        Wa, U_, Wx + (size_t)E_ * U4_, U4_, Wcomb, U4_, U4_, U_, nullptr);
    // 2. Wcomb[0:1024, :] += Uh
    add_inplace<<<(1024 * U4_) / 256, 256, 0, stream>>>(Wcomb, Uh, 1024 * U4_);
    // 3. keys = memory @ Wm
    gemm128<<<dim3(8, 25), 256, 0, stream>>>(
        memory, U_, Wm, U_, keys, U_, U_, U_, nullptr);

    // 4. persistent recurrent loop (50 steps, software grid barriers)
    decoder_loop<<<256, 256, 0, stream>>>(
        tokens, emb, Wx, bvec, Uh, Wcomb, keys, memory, h0, c0,
        hcprev, cbuf, zp, hc_all, bar);

    // 5. attn_all = hc_all @ Wa
    gemm128<<<dim3(8, 25), 256, 0, stream>>>(
        hc_all, 2048, Wa, U_, attn_all, U_, U_, 2048, nullptr);
    // 6. out = attn_all @ Wo + bo
    gemm128<<<dim3(235, 25), 256, 0, stream>>>(
        attn_all, U_, Wo, V_, out, V_, V_, U_, bo);
}

// Round 3
// 14256.497 us; speedup vs baseline: 2.9914x; 2.9914x over previous
//
#include <hip/hip_runtime.h>
#include <math.h>

#define B_  64
#define T_  50
#define S_  50
#define U_  1024
#define E_  100
#define V_  30001
#define U4_ 4096

// ---------------------------------------------------------------------------
// Generic tiled f32 GEMM: C[M,N] = A[M,K] @ B[K,N] (+ bias).
// BM=BN=128, BK=8, 256 threads, 8x8 micro-tile. M%128==0 required.
// Handles K%8!=0 (zero-padded tail), N edge, and unaligned ldb via scalars.
// ---------------------------------------------------------------------------
__global__ __launch_bounds__(256) void gemm128(
    const float* __restrict__ A, int lda,
    const float* __restrict__ Bm, int ldb,
    float* __restrict__ C, int ldc,
    int N, int K, const float* __restrict__ bias)
{
    __shared__ float As[8][132];
    __shared__ float Bs[8][132];

    const int n0  = blockIdx.x * 128;
    const int m0  = blockIdx.y * 128;
    const int tid = threadIdx.x;
    const int tx  = tid & 15, ty = tid >> 4;

    float acc[8][8];
#pragma unroll
    for (int i = 0; i < 8; ++i)
#pragma unroll
        for (int j = 0; j < 8; ++j) acc[i][j] = 0.f;

    const int ra = tid >> 1, ca = (tid & 1) * 4;
    const int rb = tid >> 5, cb = (tid & 31) * 4;
    const bool fast_b = ((ldb & 3) == 0) && (n0 + 128 <= N);

    for (int k0 = 0; k0 < K; k0 += 8) {
        const float* ap = &A[(size_t)(m0 + ra) * lda + k0 + ca];
        float4 av;
        if (k0 + 8 <= K) {
            av = *(const float4*)ap;
        } else {
            av.x = (k0 + ca + 0 < K) ? ap[0] : 0.f;
            av.y = (k0 + ca + 1 < K) ? ap[1] : 0.f;
            av.z = (k0 + ca + 2 < K) ? ap[2] : 0.f;
            av.w = (k0 + ca + 3 < K) ? ap[3] : 0.f;
        }
        As[ca + 0][ra] = av.x;
        As[ca + 1][ra] = av.y;
        As[ca + 2][ra] = av.z;
        As[ca + 3][ra] = av.w;

        float4 bv = make_float4(0.f, 0.f, 0.f, 0.f);
        if (k0 + rb < K) {
            const float* bp = &Bm[(size_t)(k0 + rb) * ldb];
            if (fast_b) {
                bv = *(const float4*)&bp[n0 + cb];
            } else {
                bv.x = (n0 + cb + 0 < N) ? bp[n0 + cb + 0] : 0.f;
                bv.y = (n0 + cb + 1 < N) ? bp[n0 + cb + 1] : 0.f;
                bv.z = (n0 + cb + 2 < N) ? bp[n0 + cb + 2] : 0.f;
                bv.w = (n0 + cb + 3 < N) ? bp[n0 + cb + 3] : 0.f;
            }
        }
        *(float4*)&Bs[rb][cb] = bv;
        __syncthreads();

#pragma unroll
        for (int kk = 0; kk < 8; ++kk) {
            float4 a0 = *(const float4*)&As[kk][ty * 4];
            float4 a1 = *(const float4*)&As[kk][64 + ty * 4];
            float4 b0 = *(const float4*)&Bs[kk][tx * 4];
            float4 b1 = *(const float4*)&Bs[kk][64 + tx * 4];
            float a_[8] = {a0.x, a0.y, a0.z, a0.w, a1.x, a1.y, a1.z, a1.w};
            float b_[8] = {b0.x, b0.y, b0.z, b0.w, b1.x, b1.y, b1.z, b1.w};
#pragma unroll
            for (int i = 0; i < 8; ++i)
#pragma unroll
                for (int j = 0; j < 8; ++j)
                    acc[i][j] = fmaf(a_[i], b_[j], acc[i][j]);
        }
        __syncthreads();
    }

#pragma unroll
    for (int i = 0; i < 8; ++i) {
        int row = m0 + ((i < 4) ? (ty * 4 + i) : (64 + ty * 4 + (i - 4)));
#pragma unroll
        for (int j = 0; j < 8; ++j) {
            int col = n0 + ((j < 4) ? (tx * 4 + j) : (64 + tx * 4 + (j - 4)));
            if (col < N) {
                float v = acc[i][j];
                if (bias) v += bias[col];
                C[(size_t)row * ldc + col] = v;
            }
        }
    }
}

__global__ void add_inplace(float* __restrict__ dst, const float* __restrict__ src, int n)
{
    int i = blockIdx.x * blockDim.x + threadIdx.x;
    if (i < n) dst[i] += src[i];
}

// x_emb[r][e] = emb[tokens[r]][e], r = b*T + t
__global__ void gather_emb(const int* __restrict__ tokens,
                           const float* __restrict__ emb,
                           float* __restrict__ xe)
{
    const int r = blockIdx.x;
    const int e = threadIdx.x;
    if (e < E_) xe[(size_t)r * E_ + e] = emb[(size_t)tokens[r] * E_ + e];
}

// ---------------------------------------------------------------------------
// Software grid barrier, fixed: RELAXED polling (no per-poll cache inv),
// one release on arrival, one acquire fence on exit.
// ---------------------------------------------------------------------------
__device__ __forceinline__ void gbar(unsigned* bar, unsigned& gen)
{
    __syncthreads();
    if (threadIdx.x == 0) {
        gen += gridDim.x;
        __hip_atomic_fetch_add(bar, 1u, __ATOMIC_RELEASE, __HIP_MEMORY_SCOPE_AGENT);
        while (__hip_atomic_load(bar, __ATOMIC_RELAXED, __HIP_MEMORY_SCOPE_AGENT) < gen)
            __builtin_amdgcn_s_sleep(2);
        __builtin_amdgcn_fence(__ATOMIC_ACQUIRE, "agent");   // one L1/L2 inv
    }
    __syncthreads();
}

// ---------------------------------------------------------------------------
// Persistent decoder loop: 50 steps, 2 phases/step.
// Phase A (256 blocks): zp[ks][64][4096] += hcprev-tile @ Wcomb-slice
// Phase BC (64 blocks): gates (c in registers) + scores/softmax/ctx
// ---------------------------------------------------------------------------
__global__ __launch_bounds__(256) void decoder_loop2(
    const float* __restrict__ zemb,   // [3200][4096]
    const float* __restrict__ Uh,
    const float* __restrict__ Wcomb,
    const float* __restrict__ keys,
    const float* __restrict__ memory,
    const float* __restrict__ h0,
    const float* __restrict__ c0,
    float* __restrict__ hcprev,   // [64][2048]
    float* __restrict__ zp,       // [8][64][4096]
    float* __restrict__ hc_all,   // [64][50][2048]
    unsigned* bar)
{
    __shared__ float As[16][68];
    __shared__ float Bs[16][132];
    __shared__ float hs[1024];
    __shared__ float sc[64];
    __shared__ float al[64];

    const int beta = blockIdx.x;
    const int tid  = threadIdx.x;
    unsigned gen = 0;

    // init: hcprev = [h0 | 0]; c-state into registers of blocks 0..63
    for (int idx = beta * 256 + tid; idx < 64 * 2048; idx += 256 * 256) {
        int row = idx >> 11, col = idx & 2047;
        hcprev[idx] = (col < 1024) ? h0[row * 1024 + col] : 0.f;
    }
    float creg[4] = {0.f, 0.f, 0.f, 0.f};
    if (beta < 64) {
#pragma unroll
        for (int i = 0; i < 4; ++i)
            creg[i] = c0[beta * U_ + tid + 256 * i];
    }
    gbar(bar, gen);

    const int nt = beta & 31, ks = beta >> 5;
    const int c0c = nt * 128;
    const int tx = tid & 31, ty = tid >> 5;
    const int arow = tid >> 2, akc = (tid & 3) * 4;
    const int bkb = tid >> 4, bcb = (tid & 15) * 8;

    for (int t = 0; t < T_; ++t) {
        const int KS = t ? 8 : 4;

        // ---------------- phase A: z partials ----------------
        if (ks < KS) {
            const float* Bz = t ? Wcomb : Uh;
            const int koff = ks * 256;
            float acc[8][4];
#pragma unroll
            for (int i = 0; i < 8; ++i)
#pragma unroll
                for (int j = 0; j < 4; ++j) acc[i][j] = 0.f;

            for (int kc0 = 0; kc0 < 256; kc0 += 16) {
                float4 av = *(const float4*)&hcprev[arow * 2048 + koff + kc0 + akc];
                As[akc + 0][arow] = av.x;
                As[akc + 1][arow] = av.y;
                As[akc + 2][arow] = av.z;
                As[akc + 3][arow] = av.w;
                const float* brow = &Bz[(size_t)(koff + kc0 + bkb) * U4_ + c0c + bcb];
                *(float4*)&Bs[bkb][bcb]     = *(const float4*)&brow[0];
                *(float4*)&Bs[bkb][bcb + 4] = *(const float4*)&brow[4];
                __syncthreads();
#pragma unroll
                for (int kk = 0; kk < 16; ++kk) {
                    float4 a0 = *(const float4*)&As[kk][ty * 8];
                    float4 a1 = *(const float4*)&As[kk][ty * 8 + 4];
                    float4 bq = *(const float4*)&Bs[kk][tx * 4];
                    float a_[8] = {a0.x, a0.y, a0.z, a0.w, a1.x, a1.y, a1.z, a1.w};
                    float b_[4] = {bq.x, bq.y, bq.z, bq.w};
#pragma unroll
                    for (int i = 0; i < 8; ++i)
#pragma unroll
                        for (int j = 0; j < 4; ++j)
                            acc[i][j] = fmaf(a_[i], b_[j], acc[i][j]);
                }
                __syncthreads();
            }
#pragma unroll
            for (int i = 0; i < 8; ++i) {
                int row = ty * 8 + i;
                *(float4*)&zp[((size_t)ks * 64 + row) * U4_ + c0c + tx * 4] =
                    make_float4(acc[i][0], acc[i][1], acc[i][2], acc[i][3]);
            }
        }
        gbar(bar, gen);

        // ---------------- phase BC: gates + attention ----------------
        if (beta < 64) {
            const int b = beta;
            const float* ze = &zemb[((size_t)b * T_ + t) * U4_];
            float hn_[4];
#pragma unroll
            for (int i = 0; i < 4; ++i) {
                const int u = tid + 256 * i;
                float zg[4];
#pragma unroll
                for (int g = 0; g < 4; ++g) {
                    const int col = g * U_ + u;
                    float a = ze[col];
                    for (int s = 0; s < KS; ++s)
                        a += zp[((size_t)s * 64 + b) * U4_ + col];
                    zg[g] = a;
                }
                const float si = 1.f / (1.f + expf(-zg[0]));
                const float sf = 1.f / (1.f + expf(-zg[1]));
                const float tg = tanhf(zg[2]);
                const float so = 1.f / (1.f + expf(-zg[3]));
                const float cn = sf * creg[i] + si * tg;
                creg[i] = cn;
                const float hn = so * tanhf(cn);
                hn_[i] = hn;
                hs[u] = hn;
            }
            __syncthreads();
#pragma unroll
            for (int i = 0; i < 4; ++i) {
                const int u = tid + 256 * i;
                hcprev[b * 2048 + u] = hn_[i];
                hc_all[((size_t)b * T_ + t) * 2048 + u] = hn_[i];
            }

            const int lane = tid & 63, w = tid >> 6;
            for (int s = w; s < S_; s += 4) {
                const float* kp = &keys[((size_t)b * S_ + s) * U_];
                float p = 0.f;
#pragma unroll
                for (int i2 = 0; i2 < 16; ++i2)
                    p = fmaf(hs[lane + 64 * i2], kp[lane + 64 * i2], p);
#pragma unroll
                for (int off = 32; off > 0; off >>= 1)
                    p += __shfl_xor(p, off);
                if (lane == 0) sc[s] = p;
            }
            __syncthreads();

            if (tid < 64) {
                float v = (lane < S_) ? sc[lane] : -INFINITY;
                float m = v;
#pragma unroll
                for (int off = 32; off > 0; off >>= 1)
                    m = fmaxf(m, __shfl_xor(m, off));
                float e = (lane < S_) ? expf(v - m) : 0.f;
                float ssum = e;
#pragma unroll
                for (int off = 32; off > 0; off >>= 1)
                    ssum += __shfl_xor(ssum, off);
                if (lane < S_) al[lane] = e / ssum;
            }
            __syncthreads();

#pragma unroll
            for (int i = 0; i < 4; ++i) {
                const int u = tid + 256 * i;
                float cacc = 0.f;
                for (int s = 0; s < S_; ++s)
                    cacc = fmaf(al[s], memory[((size_t)b * S_ + s) * U_ + u], cacc);
                hcprev[b * 2048 + U_ + u] = cacc;
                hc_all[((size_t)b * T_ + t) * 2048 + U_ + u] = cacc;
            }
        }
        gbar(bar, gen);
    }
}

// ---------------------------------------------------------------------------
extern "C" void kernel_launch(void* const* d_in, const int* in_sizes, int n_in,
                              void* d_out, int out_size, void* d_ws, size_t ws_size,
                              hipStream_t stream)
{
    const int*   tokens = (const int*)  d_in[0];
    const float* memory = (const float*)d_in[1];
    const float* h0     = (const float*)d_in[2];
    const float* c0     = (const float*)d_in[3];
    const float* emb    = (const float*)d_in[4];
    const float* Wx     = (const float*)d_in[5];
    const float* Uh     = (const float*)d_in[6];
    const float* bvec   = (const float*)d_in[7];
    const float* Wm     = (const float*)d_in[8];
    const float* Wa     = (const float*)d_in[9];
    const float* Wo     = (const float*)d_in[10];
    const float* bo     = (const float*)d_in[11];
    float* out = (float*)d_out;

    // workspace layout (floats)
    float* ws = (float*)d_ws;
    size_t off = 0;
    float* keys     = ws + off; off += (size_t)B_ * S_ * U_;   // 3,276,800
    float* Wcomb    = ws + off; off += (size_t)2048 * U4_;     // 8,388,608
    float* hc_all   = ws + off; off += (size_t)B_ * T_ * 2048; // 6,553,600
    float* zp       = ws + off; off += (size_t)8 * B_ * U4_;   // 2,097,152
    float* hcprev   = ws + off; off += (size_t)B_ * 2048;      //   131,072
    float* x_emb    = ws + off; off += (size_t)B_ * T_ * E_;   //   320,000
    unsigned* bar   = (unsigned*)(ws + off); off += 64;
    float* attn_all = keys;          // keys dead after loop; alias
    float* zemb     = out;           // [3200][4096] scratch inside d_out (dead
                                     // before the final Wo GEMM overwrites out)

    hipMemsetAsync(bar, 0, sizeof(unsigned), stream);

    // pre-loop (all parallel-friendly GEMMs)
    gather_emb<<<B_ * T_, 128, 0, stream>>>(tokens, emb, x_emb);
    // zemb = x_emb @ Wx[0:100] + b   (M=3200, N=4096, K=100)
    gemm128<<<dim3(32, 25), 256, 0, stream>>>(
        x_emb, E_, Wx, U4_, zemb, U4_, U4_, E_, bvec);
    // Wcomb = Wa @ Wx[100:1124]   (M=2048, N=4096, K=1024)
    gemm128<<<dim3(32, 16), 256, 0, stream>>>(
        Wa, U_, Wx + (size_t)E_ * U4_, U4_, Wcomb, U4_, U4_, U_, nullptr);
    // Wcomb[0:1024] += Uh
    add_inplace<<<(1024 * U4_) / 256, 256, 0, stream>>>(Wcomb, Uh, 1024 * U4_);
    // keys = memory @ Wm   (M=3200, N=1024, K=1024)
    gemm128<<<dim3(8, 25), 256, 0, stream>>>(
        memory, U_, Wm, U_, keys, U_, U_, U_, nullptr);

    // persistent recurrent loop
    decoder_loop2<<<256, 256, 0, stream>>>(
        zemb, Uh, Wcomb, keys, memory, h0, c0,
        hcprev, zp, hc_all, bar);

    // post-loop
    // attn_all = hc_all @ Wa   (M=3200, N=1024, K=2048)
    gemm128<<<dim3(8, 25), 256, 0, stream>>>(
        hc_all, 2048, Wa, U_, attn_all, U_, U_, 2048, nullptr);
    // out = attn_all @ Wo + bo   (M=3200, N=30001, K=1024)
    gemm128<<<dim3(235, 25), 256, 0, stream>>>(
        attn_all, U_, Wo, V_, out, V_, V_, U_, bo);
}

// Round 6
// 8209.917 us; speedup vs baseline: 5.1946x; 1.7365x over previous
//
#include <hip/hip_runtime.h>
#include <math.h>

#define B_  64
#define T_  50
#define S_  50
#define U_  1024
#define E_  100
#define V_  30001
#define U4_ 4096
#define VP_ 30080   // V padded to a multiple of 128 for bf16 staging alignment

typedef __bf16 bf16_t;
typedef bf16_t bf16x8 __attribute__((ext_vector_type(8)));
typedef float  f32x4  __attribute__((ext_vector_type(4)));

// ---------------------------------------------------------------------------
// Generic tiled f32 GEMM: C[M,N] = A[M,K] @ B[K,N] (+ bias).
// BM=BN=128, BK=8, 256 threads, 8x8 micro-tile. M%128==0 required.
// ---------------------------------------------------------------------------
__global__ __launch_bounds__(256) void gemm128(
    const float* __restrict__ A, int lda,
    const float* __restrict__ Bm, int ldb,
    float* __restrict__ C, int ldc,
    int N, int K, const float* __restrict__ bias)
{
    __shared__ float As[8][132];
    __shared__ float Bs[8][132];

    const int n0  = blockIdx.x * 128;
    const int m0  = blockIdx.y * 128;
    const int tid = threadIdx.x;
    const int tx  = tid & 15, ty = tid >> 4;

    float acc[8][8];
#pragma unroll
    for (int i = 0; i < 8; ++i)
#pragma unroll
        for (int j = 0; j < 8; ++j) acc[i][j] = 0.f;

    const int ra = tid >> 1, ca = (tid & 1) * 4;
    const int rb = tid >> 5, cb = (tid & 31) * 4;
    const bool fast_b = ((ldb & 3) == 0) && (n0 + 128 <= N);

    for (int k0 = 0; k0 < K; k0 += 8) {
        const float* ap = &A[(size_t)(m0 + ra) * lda + k0 + ca];
        float4 av;
        if (k0 + 8 <= K) {
            av = *(const float4*)ap;
        } else {
            av.x = (k0 + ca + 0 < K) ? ap[0] : 0.f;
            av.y = (k0 + ca + 1 < K) ? ap[1] : 0.f;
            av.z = (k0 + ca + 2 < K) ? ap[2] : 0.f;
            av.w = (k0 + ca + 3 < K) ? ap[3] : 0.f;
        }
        As[ca + 0][ra] = av.x;
        As[ca + 1][ra] = av.y;
        As[ca + 2][ra] = av.z;
        As[ca + 3][ra] = av.w;

        float4 bv = make_float4(0.f, 0.f, 0.f, 0.f);
        if (k0 + rb < K) {
            const float* bp = &Bm[(size_t)(k0 + rb) * ldb];
            if (fast_b) {
                bv = *(const float4*)&bp[n0 + cb];
            } else {
                bv.x = (n0 + cb + 0 < N) ? bp[n0 + cb + 0] : 0.f;
                bv.y = (n0 + cb + 1 < N) ? bp[n0 + cb + 1] : 0.f;
                bv.z = (n0 + cb + 2 < N) ? bp[n0 + cb + 2] : 0.f;
                bv.w = (n0 + cb + 3 < N) ? bp[n0 + cb + 3] : 0.f;
            }
        }
        *(float4*)&Bs[rb][cb] = bv;
        __syncthreads();

#pragma unroll
        for (int kk = 0; kk < 8; ++kk) {
            float4 a0 = *(const float4*)&As[kk][ty * 4];
            float4 a1 = *(const float4*)&As[kk][64 + ty * 4];
            float4 b0 = *(const float4*)&Bs[kk][tx * 4];
            float4 b1 = *(const float4*)&Bs[kk][64 + tx * 4];
            float a_[8] = {a0.x, a0.y, a0.z, a0.w, a1.x, a1.y, a1.z, a1.w};
            float b_[8] = {b0.x, b0.y, b0.z, b0.w, b1.x, b1.y, b1.z, b1.w};
#pragma unroll
            for (int i = 0; i < 8; ++i)
#pragma unroll
                for (int j = 0; j < 8; ++j)
                    acc[i][j] = fmaf(a_[i], b_[j], acc[i][j]);
        }
        __syncthreads();
    }

#pragma unroll
    for (int i = 0; i < 8; ++i) {
        int row = m0 + ((i < 4) ? (ty * 4 + i) : (64 + ty * 4 + (i - 4)));
#pragma unroll
        for (int j = 0; j < 8; ++j) {
            int col = n0 + ((j < 4) ? (tx * 4 + j) : (64 + tx * 4 + (j - 4)));
            if (col < N) {
                float v = acc[i][j];
                if (bias) v += bias[col];
                C[(size_t)row * ldc + col] = v;
            }
        }
    }
}

__global__ void add_inplace(float* __restrict__ dst, const float* __restrict__ src, int n)
{
    int i = blockIdx.x * blockDim.x + threadIdx.x;
    if (i < n) dst[i] += src[i];
}

__global__ void gather_emb(const int* __restrict__ tokens,
                           const float* __restrict__ emb,
                           float* __restrict__ xe)
{
    const int r = blockIdx.x;
    const int e = threadIdx.x;
    if (e < E_) xe[(size_t)r * E_ + e] = emb[(size_t)tokens[r] * E_ + e];
}

__global__ void cast_bf16(const float* __restrict__ src, bf16_t* __restrict__ dst, int n)
{
    int i = blockIdx.x * blockDim.x + threadIdx.x;
    const int stride = gridDim.x * blockDim.x;
    for (; i < n; i += stride) dst[i] = (bf16_t)src[i];
}

// Wo [1024][30001] f32 -> [1024][VP_] bf16, zero-padded tail columns
__global__ void cast_wo_bf16(const float* __restrict__ wo, bf16_t* __restrict__ dst)
{
    const int col = blockIdx.x * 256 + threadIdx.x;
    const int k   = blockIdx.y;
    if (col < VP_)
        dst[(size_t)k * VP_ + col] =
            (col < V_) ? (bf16_t)wo[(size_t)k * V_ + col] : (bf16_t)0.f;
}

// ---------------------------------------------------------------------------
// Split-K GEMM for t=0: zp[(ks*64+b)*4096+n] = sum_{k in slice} h0[b][k]*Uh[k][n]
// ---------------------------------------------------------------------------
__global__ __launch_bounds__(256) void zgemm_partial(
    const float* __restrict__ A, int lda,
    const float* __restrict__ Bm,
    float* __restrict__ zp)
{
    __shared__ float As[64][17];
    __shared__ float Bs[16][68];

    const int n0     = blockIdx.x * 64;
    const int ks     = blockIdx.y;
    const int k_base = ks * 256;
    const int tid    = threadIdx.x;
    const int tx     = tid & 15, ty = tid >> 4;

    float acc[4][4];
#pragma unroll
    for (int i = 0; i < 4; ++i)
#pragma unroll
        for (int j = 0; j < 4; ++j) acc[i][j] = 0.f;

    const int ra = tid >> 2, ca = (tid & 3) * 4;
    const int rb = tid >> 4, cb = (tid & 15) * 4;

    for (int kt = 0; kt < 16; ++kt) {
        const int k0 = k_base + kt * 16;
        float4 av = *(const float4*)&A[(size_t)ra * lda + k0 + ca];
        As[ra][ca + 0] = av.x;
        As[ra][ca + 1] = av.y;
        As[ra][ca + 2] = av.z;
        As[ra][ca + 3] = av.w;
        float4 bv = *(const float4*)&Bm[(size_t)(k0 + rb) * U4_ + n0 + cb];
        *(float4*)&Bs[rb][cb] = bv;
        __syncthreads();
#pragma unroll
        for (int kk = 0; kk < 16; ++kk) {
            float a_[4];
#pragma unroll
            for (int i = 0; i < 4; ++i) a_[i] = As[ty * 4 + i][kk];
            float4 bq = *(const float4*)&Bs[kk][tx * 4];
            float b_[4] = {bq.x, bq.y, bq.z, bq.w};
#pragma unroll
            for (int i = 0; i < 4; ++i)
#pragma unroll
                for (int j = 0; j < 4; ++j)
                    acc[i][j] = fmaf(a_[i], b_[j], acc[i][j]);
        }
        __syncthreads();
    }

#pragma unroll
    for (int i = 0; i < 4; ++i)
        *(float4*)&zp[((size_t)ks * 64 + ty * 4 + i) * U4_ + n0 + tx * 4] =
            make_float4(acc[i][0], acc[i][1], acc[i][2], acc[i][3]);
}

// ---------------------------------------------------------------------------
// Grid barrier — ROUND-3-PROVEN protocol: release add, relaxed spin, acquire
// fence on exit (invalidates L1/L2; LDS-resident weights are immune).
// ---------------------------------------------------------------------------
__device__ __forceinline__ void gbar(unsigned* bar, unsigned& gen)
{
    __syncthreads();
    if (threadIdx.x == 0) {
        gen += gridDim.x;
        __hip_atomic_fetch_add(bar, 1u, __ATOMIC_RELEASE, __HIP_MEMORY_SCOPE_AGENT);
        while (__hip_atomic_load(bar, __ATOMIC_RELAXED, __HIP_MEMORY_SCOPE_AGENT) < gen)
            __builtin_amdgcn_s_sleep(2);
        __builtin_amdgcn_fence(__ATOMIC_ACQUIRE, "agent");
    }
    __syncthreads();
}

// ---------------------------------------------------------------------------
// Persistent decoder loop, Wcomb resident in LDS (128 KB/block slice).
// grid = 256 blocks x 512 threads; block beta: ks = beta>>5, nt = beta&31.
// Plain loads/stores everywhere; coherence via gbar's release+acquire.
// ---------------------------------------------------------------------------
__global__ __launch_bounds__(512) void decoder_loop3(
    const float* __restrict__ zemb,   // [3200][4096]
    const float* __restrict__ Wcomb,  // [2048][4096]
    const float* __restrict__ keys,   // [64][50][1024]
    const float* __restrict__ memory, // [64][50][1024]
    const float* __restrict__ c0,
    float* __restrict__ hcprev,       // [64][2048]
    float* __restrict__ zp,           // [8][64][4096]
    float* __restrict__ hc_all,       // [64][50][2048]
    unsigned* bar)
{
    __shared__ float Bw[256 * 128];   // 128 KB persistent weight slice
    __shared__ float As[2][16][68];
    __shared__ float hs[1024];
    __shared__ float sc[64];
    __shared__ float al[64];

    const int beta = blockIdx.x;
    const int tid  = threadIdx.x;
    unsigned gen = 0;

    const int nt = beta & 31, ks = beta >> 5;
    const int koff = ks * 256;
    const int c0c  = nt * 128;

    // ---- load persistent Wcomb slice into LDS (coalesced, once) ----
    {
        const int k_sub = tid >> 5;          // 0..15
        const int c4    = (tid & 31) * 4;    // 0..124
#pragma unroll
        for (int it = 0; it < 16; ++it) {
            int k = it * 16 + k_sub;
            *(float4*)&Bw[k * 128 + c4] =
                *(const float4*)&Wcomb[(size_t)(koff + k) * U4_ + c0c + c4];
        }
    }

    // ---- c-state in registers of blocks 0..63 ----
    float creg[2] = {0.f, 0.f};
    if (beta < 64) {
#pragma unroll
        for (int i = 0; i < 2; ++i)
            creg[i] = c0[beta * U_ + tid + 512 * i];
    }
    __syncthreads();

    // micro-tile indices (phase A): 64 rows x 128 cols, 4x4 per thread
    const int tx = tid & 31;
    const int ty = tid >> 5;
    // staging indices: chunk = 64 rows x 16 k, 2 elems/thread
    const int srow = tid >> 3;
    const int sk   = (tid & 7) * 2;

    for (int t = 0; t < T_; ++t) {
        const int KS = t ? 8 : 4;

        // ---------------- phase A (t>=1): z partials from LDS weights -------
        if (t) {
            float acc[4][4];
#pragma unroll
            for (int i = 0; i < 4; ++i)
#pragma unroll
                for (int j = 0; j < 4; ++j) acc[i][j] = 0.f;

            const float* arow_p = &hcprev[srow * 2048 + koff];
            float v0 = arow_p[sk];
            float v1 = arow_p[sk + 1];
            As[0][sk][srow]     = v0;
            As[0][sk + 1][srow] = v1;
            float p0 = arow_p[16 + sk];
            float p1 = arow_p[16 + sk + 1];
            __syncthreads();

            for (int kc = 0; kc < 16; ++kc) {
                const int cur = kc & 1;
                const float* bwp = &Bw[(kc * 16) * 128];
#pragma unroll
                for (int kk = 0; kk < 16; ++kk) {
                    float4 af = *(const float4*)&As[cur][kk][ty * 4];
                    float4 bf = *(const float4*)&bwp[kk * 128 + tx * 4];
                    float a_[4] = {af.x, af.y, af.z, af.w};
                    float b_[4] = {bf.x, bf.y, bf.z, bf.w};
#pragma unroll
                    for (int i = 0; i < 4; ++i)
#pragma unroll
                        for (int j = 0; j < 4; ++j)
                            acc[i][j] = fmaf(a_[i], b_[j], acc[i][j]);
                }
                if (kc < 15) {
                    As[cur ^ 1][sk][srow]     = p0;
                    As[cur ^ 1][sk + 1][srow] = p1;
                    if (kc < 14) {
                        p0 = arow_p[(kc + 2) * 16 + sk];
                        p1 = arow_p[(kc + 2) * 16 + sk + 1];
                    }
                }
                __syncthreads();
            }
#pragma unroll
            for (int i = 0; i < 4; ++i) {
                int m = ty * 4 + i;
                *(float4*)&zp[((size_t)ks * 64 + m) * U4_ + c0c + tx * 4] =
                    make_float4(acc[i][0], acc[i][1], acc[i][2], acc[i][3]);
            }
            gbar(bar, gen);
        }

        // ---------------- phase BC: gates + attention (blocks < 64) ---------
        if (beta < 64) {
            const int b = beta;
            const float* ze = &zemb[((size_t)b * T_ + t) * U4_];
            float hn_[2];
#pragma unroll
            for (int i = 0; i < 2; ++i) {
                const int u = tid + 512 * i;
                float zg[4];
#pragma unroll
                for (int g = 0; g < 4; ++g) {
                    const int col = g * U_ + u;
                    float a = ze[col];
                    for (int s = 0; s < KS; ++s)
                        a += zp[((size_t)s * 64 + b) * U4_ + col];
                    zg[g] = a;
                }
                const float si = 1.f / (1.f + expf(-zg[0]));
                const float sf = 1.f / (1.f + expf(-zg[1]));
                const float tg = tanhf(zg[2]);
                const float so = 1.f / (1.f + expf(-zg[3]));
                const float cn = sf * creg[i] + si * tg;
                creg[i] = cn;
                const float hn = so * tanhf(cn);
                hn_[i] = hn;
                hs[u] = hn;
            }
            __syncthreads();
#pragma unroll
            for (int i = 0; i < 2; ++i) {
                const int u = tid + 512 * i;
                hcprev[b * 2048 + u] = hn_[i];
                hc_all[((size_t)b * T_ + t) * 2048 + u] = hn_[i];
            }

            const int lane = tid & 63, w = tid >> 6;  // 8 waves
            for (int s = w; s < S_; s += 8) {
                const float* kp = &keys[((size_t)b * S_ + s) * U_];
                float p = 0.f;
#pragma unroll
                for (int ii = 0; ii < 16; ++ii)
                    p = fmaf(hs[lane + 64 * ii], kp[lane + 64 * ii], p);
#pragma unroll
                for (int off = 32; off > 0; off >>= 1)
                    p += __shfl_xor(p, off);
                if (lane == 0) sc[s] = p;
            }
            __syncthreads();

            if (tid < 64) {
                float v = (lane < S_) ? sc[lane] : -INFINITY;
                float m = v;
#pragma unroll
                for (int off = 32; off > 0; off >>= 1)
                    m = fmaxf(m, __shfl_xor(m, off));
                float e = (lane < S_) ? expf(v - m) : 0.f;
                float ssum = e;
#pragma unroll
                for (int off = 32; off > 0; off >>= 1)
                    ssum += __shfl_xor(ssum, off);
                if (lane < S_) al[lane] = e / ssum;
            }
            __syncthreads();

#pragma unroll
            for (int i = 0; i < 2; ++i) {
                const int u = tid + 512 * i;
                float cacc = 0.f;
                for (int s = 0; s < S_; ++s)
                    cacc = fmaf(al[s], memory[((size_t)b * S_ + s) * U_ + u], cacc);
                hcprev[b * 2048 + U_ + u] = cacc;
                hc_all[((size_t)b * T_ + t) * 2048 + U_ + u] = cacc;
            }
        }
        gbar(bar, gen);
    }
}

// ---------------------------------------------------------------------------
// bf16 MFMA GEMM for the output projection: C[3200][V] = A[3200][1024] @
// B[1024][VP_] + bias. 128x128 tile, 4 waves (2x2), 16x16x32 MFMA.
// Fragment maps (guide-verified): A lane: row=l&15, k=(l>>4)*8+j;
// B lane: k=(l>>4)*8+j, col=l&15; C/D: col=l&15, row=(l>>4)*4+reg.
// ---------------------------------------------------------------------------
__global__ __launch_bounds__(256) void gemm_wo_mfma(
    const bf16_t* __restrict__ A,    // [3200][1024] bf16
    const bf16_t* __restrict__ Bw,   // [1024][VP_]  bf16 (padded)
    const float*  __restrict__ bias, // [V_]
    float* __restrict__ C)           // [3200][V_]
{
    __shared__ bf16_t As[128][40];   // [m][k], +8 pad (2-way bank, free)
    __shared__ bf16_t Bs[128][40];   // [n][k] transposed, +8 pad

    const int n0  = blockIdx.x * 128;
    const int m0  = blockIdx.y * 128;
    const int tid = threadIdx.x;
    const int wave = tid >> 6, lane = tid & 63;
    const int wr = wave >> 1, wc = wave & 1;   // 2x2 wave grid, 64x64 each
    const int lr = lane & 15;
    const int lk = lane >> 4;

    f32x4 acc[4][4] = {};   // acc[m][n], accumulates across K (guide recipe)

    // staging indices
    const int ar = tid >> 1;            // 0..127 (A row)
    const int ak = (tid & 1) * 16;      // 0/16   (A k half)
    const int bk = tid >> 3;            // 0..31  (B k row)
    const int bn = (tid & 7) * 16;      // 0..112 (B n base)

    for (int k0 = 0; k0 < U_; k0 += 32) {
        // stage A tile (each thread: 16 contiguous bf16 = 2x16B)
        {
            const bf16_t* ap = &A[(size_t)(m0 + ar) * U_ + k0 + ak];
            *(bf16x8*)&As[ar][ak]     = *(const bf16x8*)ap;
            *(bf16x8*)&As[ar][ak + 8] = *(const bf16x8*)(ap + 8);
        }
        // stage B tile transposed: Bs[n][k] <- Bw[k0+bk][n0+bn+i]
        {
            const bf16_t* bp = &Bw[(size_t)(k0 + bk) * VP_ + n0 + bn];
            bf16x8 v0 = *(const bf16x8*)bp;
            bf16x8 v1 = *(const bf16x8*)(bp + 8);
#pragma unroll
            for (int i = 0; i < 8; ++i) Bs[bn + i][bk] = v0[i];
#pragma unroll
            for (int i = 0; i < 8; ++i) Bs[bn + 8 + i][bk] = v1[i];
        }
        __syncthreads();

        bf16x8 af[4], bf[4];
#pragma unroll
        for (int m = 0; m < 4; ++m)
            af[m] = *(const bf16x8*)&As[wr * 64 + m * 16 + lr][lk * 8];
#pragma unroll
        for (int n = 0; n < 4; ++n)
            bf[n] = *(const bf16x8*)&Bs[wc * 64 + n * 16 + lr][lk * 8];
#pragma unroll
        for (int m = 0; m < 4; ++m)
#pragma unroll
            for (int n = 0; n < 4; ++n)
                acc[m][n] = __builtin_amdgcn_mfma_f32_16x16x32_bf16(
                    af[m], bf[n], acc[m][n], 0, 0, 0);
        __syncthreads();
    }

    // epilogue
#pragma unroll
    for (int m = 0; m < 4; ++m) {
        const int row = m0 + wr * 64 + m * 16 + lk * 4;
#pragma unroll
        for (int n = 0; n < 4; ++n) {
            const int col = n0 + wc * 64 + n * 16 + lr;
            if (col < V_) {
                const float bb = bias[col];
#pragma unroll
                for (int r = 0; r < 4; ++r)
                    C[(size_t)(row + r) * V_ + col] = acc[m][n][r] + bb;
            }
        }
    }
}

// ---------------------------------------------------------------------------
extern "C" void kernel_launch(void* const* d_in, const int* in_sizes, int n_in,
                              void* d_out, int out_size, void* d_ws, size_t ws_size,
                              hipStream_t stream)
{
    const int*   tokens = (const int*)  d_in[0];
    const float* memory = (const float*)d_in[1];
    const float* h0     = (const float*)d_in[2];
    const float* c0     = (const float*)d_in[3];
    const float* emb    = (const float*)d_in[4];
    const float* Wx     = (const float*)d_in[5];
    const float* Uh     = (const float*)d_in[6];
    const float* bvec   = (const float*)d_in[7];
    const float* Wm     = (const float*)d_in[8];
    const float* Wa     = (const float*)d_in[9];
    const float* Wo     = (const float*)d_in[10];
    const float* bo     = (const float*)d_in[11];
    float* out = (float*)d_out;

    // workspace layout (floats)
    float* ws = (float*)d_ws;
    size_t off = 0;
    float* keys     = ws + off; off += (size_t)B_ * S_ * U_;   // 3,276,800
    float* Wcomb    = ws + off; off += (size_t)2048 * U4_;     // 8,388,608
    float* hc_all   = ws + off; off += (size_t)B_ * T_ * 2048; // 6,553,600
    float* zp       = ws + off; off += (size_t)8 * B_ * U4_;   // 2,097,152
    float* hcprev   = ws + off; off += (size_t)B_ * 2048;      //   131,072
    float* x_emb    = ws + off; off += (size_t)B_ * T_ * E_;   //   320,000
    unsigned* bar   = (unsigned*)(ws + off); off += 64;
    bf16_t* wo_bf   = (bf16_t*)(ws + off); off += (size_t)1024 * VP_ / 2; // 61.6MB
    const size_t need_bytes = off * sizeof(float);

    float* attn_all = keys;            // keys dead after loop; alias
    bf16_t* abf     = (bf16_t*)zp;     // zp dead after loop; 6.55MB <= 8.39MB
    float* zemb     = out;             // scratch inside d_out (dead before Wo GEMM)

    const bool use_mfma = (ws_size >= need_bytes);

    (void)hipMemsetAsync(bar, 0, sizeof(unsigned), stream);

    // pre-loop GEMMs
    gather_emb<<<B_ * T_, 128, 0, stream>>>(tokens, emb, x_emb);
    // zemb = x_emb @ Wx[0:100] + b
    gemm128<<<dim3(32, 25), 256, 0, stream>>>(
        x_emb, E_, Wx, U4_, zemb, U4_, U4_, E_, bvec);
    // Wcomb = Wa @ Wx[100:1124]
    gemm128<<<dim3(32, 16), 256, 0, stream>>>(
        Wa, U_, Wx + (size_t)E_ * U4_, U4_, Wcomb, U4_, U4_, U_, nullptr);
    // Wcomb[0:1024] += Uh
    add_inplace<<<(1024 * U4_) / 256, 256, 0, stream>>>(Wcomb, Uh, 1024 * U4_);
    // keys = memory @ Wm
    gemm128<<<dim3(8, 25), 256, 0, stream>>>(
        memory, U_, Wm, U_, keys, U_, U_, U_, nullptr);
    // t=0 z-partials: zp[0..3] = h0 @ Uh  (KS=4)
    zgemm_partial<<<dim3(64, 4), 256, 0, stream>>>(h0, U_, Uh, zp);
    // Wo -> bf16 (independent of the loop)
    if (use_mfma)
        cast_wo_bf16<<<dim3((VP_ + 255) / 256, 1024), 256, 0, stream>>>(Wo, wo_bf);

    // persistent recurrent loop
    decoder_loop3<<<256, 512, 0, stream>>>(
        zemb, Wcomb, keys, memory, c0, hcprev, zp, hc_all, bar);

    // post-loop
    // attn_all = hc_all @ Wa
    gemm128<<<dim3(8, 25), 256, 0, stream>>>(
        hc_all, 2048, Wa, U_, attn_all, U_, U_, 2048, nullptr);

    if (use_mfma) {
        cast_bf16<<<2048, 256, 0, stream>>>(attn_all, abf, B_ * T_ * U_);
        gemm_wo_mfma<<<dim3(VP_ / 128, 25), 256, 0, stream>>>(abf, wo_bf, bo, out);
    } else {
        gemm128<<<dim3(235, 25), 256, 0, stream>>>(
            attn_all, U_, Wo, V_, out, V_, V_, U_, bo);
    }
}

// Round 8
// 7125.433 us; speedup vs baseline: 5.9852x; 1.1522x over previous
//
#include <hip/hip_runtime.h>
#include <math.h>

#define B_  64
#define T_  50
#define S_  50
#define U_  1024
#define E_  100
#define V_  30001
#define U4_ 4096
#define VP_ 30080   // V padded to a multiple of 128 for bf16 staging alignment

typedef __bf16 bf16_t;
typedef bf16_t bf16x8 __attribute__((ext_vector_type(8)));
typedef float  f32x4  __attribute__((ext_vector_type(4)));

// ---------------------------------------------------------------------------
// Generic tiled f32 GEMM: C[M,N] = A[M,K] @ B[K,N] (+ bias).
// BM=BN=128, BK=8, 256 threads, 8x8 micro-tile. M%128==0 required.
// ---------------------------------------------------------------------------
__global__ __launch_bounds__(256) void gemm128(
    const float* __restrict__ A, int lda,
    const float* __restrict__ Bm, int ldb,
    float* __restrict__ C, int ldc,
    int N, int K, const float* __restrict__ bias)
{
    __shared__ float As[8][132];
    __shared__ float Bs[8][132];

    const int n0  = blockIdx.x * 128;
    const int m0  = blockIdx.y * 128;
    const int tid = threadIdx.x;
    const int tx  = tid & 15, ty = tid >> 4;

    float acc[8][8];
#pragma unroll
    for (int i = 0; i < 8; ++i)
#pragma unroll
        for (int j = 0; j < 8; ++j) acc[i][j] = 0.f;

    const int ra = tid >> 1, ca = (tid & 1) * 4;
    const int rb = tid >> 5, cb = (tid & 31) * 4;
    const bool fast_b = ((ldb & 3) == 0) && (n0 + 128 <= N);

    for (int k0 = 0; k0 < K; k0 += 8) {
        const float* ap = &A[(size_t)(m0 + ra) * lda + k0 + ca];
        float4 av;
        if (k0 + 8 <= K) {
            av = *(const float4*)ap;
        } else {
            av.x = (k0 + ca + 0 < K) ? ap[0] : 0.f;
            av.y = (k0 + ca + 1 < K) ? ap[1] : 0.f;
            av.z = (k0 + ca + 2 < K) ? ap[2] : 0.f;
            av.w = (k0 + ca + 3 < K) ? ap[3] : 0.f;
        }
        As[ca + 0][ra] = av.x;
        As[ca + 1][ra] = av.y;
        As[ca + 2][ra] = av.z;
        As[ca + 3][ra] = av.w;

        float4 bv = make_float4(0.f, 0.f, 0.f, 0.f);
        if (k0 + rb < K) {
            const float* bp = &Bm[(size_t)(k0 + rb) * ldb];
            if (fast_b) {
                bv = *(const float4*)&bp[n0 + cb];
            } else {
                bv.x = (n0 + cb + 0 < N) ? bp[n0 + cb + 0] : 0.f;
                bv.y = (n0 + cb + 1 < N) ? bp[n0 + cb + 1] : 0.f;
                bv.z = (n0 + cb + 2 < N) ? bp[n0 + cb + 2] : 0.f;
                bv.w = (n0 + cb + 3 < N) ? bp[n0 + cb + 3] : 0.f;
            }
        }
        *(float4*)&Bs[rb][cb] = bv;
        __syncthreads();

#pragma unroll
        for (int kk = 0; kk < 8; ++kk) {
            float4 a0 = *(const float4*)&As[kk][ty * 4];
            float4 a1 = *(const float4*)&As[kk][64 + ty * 4];
            float4 b0 = *(const float4*)&Bs[kk][tx * 4];
            float4 b1 = *(const float4*)&Bs[kk][64 + tx * 4];
            float a_[8] = {a0.x, a0.y, a0.z, a0.w, a1.x, a1.y, a1.z, a1.w};
            float b_[8] = {b0.x, b0.y, b0.z, b0.w, b1.x, b1.y, b1.z, b1.w};
#pragma unroll
            for (int i = 0; i < 8; ++i)
#pragma unroll
                for (int j = 0; j < 8; ++j)
                    acc[i][j] = fmaf(a_[i], b_[j], acc[i][j]);
        }
        __syncthreads();
    }

#pragma unroll
    for (int i = 0; i < 8; ++i) {
        int row = m0 + ((i < 4) ? (ty * 4 + i) : (64 + ty * 4 + (i - 4)));
#pragma unroll
        for (int j = 0; j < 8; ++j) {
            int col = n0 + ((j < 4) ? (tx * 4 + j) : (64 + tx * 4 + (j - 4)));
            if (col < N) {
                float v = acc[i][j];
                if (bias) v += bias[col];
                C[(size_t)row * ldc + col] = v;
            }
        }
    }
}

__global__ void add_inplace(float* __restrict__ dst, const float* __restrict__ src, int n)
{
    int i = blockIdx.x * blockDim.x + threadIdx.x;
    if (i < n) dst[i] += src[i];
}

__global__ void gather_emb(const int* __restrict__ tokens,
                           const float* __restrict__ emb,
                           float* __restrict__ xe)
{
    const int r = blockIdx.x;
    const int e = threadIdx.x;
    if (e < E_) xe[(size_t)r * E_ + e] = emb[(size_t)tokens[r] * E_ + e];
}

__global__ void cast_bf16(const float* __restrict__ src, bf16_t* __restrict__ dst, int n)
{
    int i = blockIdx.x * blockDim.x + threadIdx.x;
    const int stride = gridDim.x * blockDim.x;
    for (; i < n; i += stride) dst[i] = (bf16_t)src[i];
}

// Wo [1024][30001] f32 -> [1024][VP_] bf16, zero-padded tail columns
__global__ void cast_wo_bf16(const float* __restrict__ wo, bf16_t* __restrict__ dst)
{
    const int col = blockIdx.x * 256 + threadIdx.x;
    const int k   = blockIdx.y;
    if (col < VP_)
        dst[(size_t)k * VP_ + col] =
            (col < V_) ? (bf16_t)wo[(size_t)k * V_ + col] : (bf16_t)0.f;
}

// ---------------------------------------------------------------------------
// Split-K GEMM for t=0: zp[(ks*64+b)*4096+n] = sum_{k in slice} h0[b][k]*Uh[k][n]
// ---------------------------------------------------------------------------
__global__ __launch_bounds__(256) void zgemm_partial(
    const float* __restrict__ A, int lda,
    const float* __restrict__ Bm,
    float* __restrict__ zp)
{
    __shared__ float As[64][17];
    __shared__ float Bs[16][68];

    const int n0     = blockIdx.x * 64;
    const int ks     = blockIdx.y;
    const int k_base = ks * 256;
    const int tid    = threadIdx.x;
    const int tx     = tid & 15, ty = tid >> 4;

    float acc[4][4];
#pragma unroll
    for (int i = 0; i < 4; ++i)
#pragma unroll
        for (int j = 0; j < 4; ++j) acc[i][j] = 0.f;

    const int ra = tid >> 2, ca = (tid & 3) * 4;
    const int rb = tid >> 4, cb = (tid & 15) * 4;

    for (int kt = 0; kt < 16; ++kt) {
        const int k0 = k_base + kt * 16;
        float4 av = *(const float4*)&A[(size_t)ra * lda + k0 + ca];
        As[ra][ca + 0] = av.x;
        As[ra][ca + 1] = av.y;
        As[ra][ca + 2] = av.z;
        As[ra][ca + 3] = av.w;
        float4 bv = *(const float4*)&Bm[(size_t)(k0 + rb) * U4_ + n0 + cb];
        *(float4*)&Bs[rb][cb] = bv;
        __syncthreads();
#pragma unroll
        for (int kk = 0; kk < 16; ++kk) {
            float a_[4];
#pragma unroll
            for (int i = 0; i < 4; ++i) a_[i] = As[ty * 4 + i][kk];
            float4 bq = *(const float4*)&Bs[kk][tx * 4];
            float b_[4] = {bq.x, bq.y, bq.z, bq.w};
#pragma unroll
            for (int i = 0; i < 4; ++i)
#pragma unroll
                for (int j = 0; j < 4; ++j)
                    acc[i][j] = fmaf(a_[i], b_[j], acc[i][j]);
        }
        __syncthreads();
    }

#pragma unroll
    for (int i = 0; i < 4; ++i)
        *(float4*)&zp[((size_t)ks * 64 + ty * 4 + i) * U4_ + n0 + tx * 4] =
            make_float4(acc[i][0], acc[i][1], acc[i][2], acc[i][3]);
}

// ---------------------------------------------------------------------------
// Grid barrier — PROVEN protocol (r3/r6): release add, relaxed spin, acquire
// fence on exit (invalidates L1/L2; LDS-resident weights are immune).
// ---------------------------------------------------------------------------
__device__ __forceinline__ void gbar(unsigned* bar, unsigned& gen)
{
    __syncthreads();
    if (threadIdx.x == 0) {
        gen += gridDim.x;
        __hip_atomic_fetch_add(bar, 1u, __ATOMIC_RELEASE, __HIP_MEMORY_SCOPE_AGENT);
        while (__hip_atomic_load(bar, __ATOMIC_RELAXED, __HIP_MEMORY_SCOPE_AGENT) < gen)
            __builtin_amdgcn_s_sleep(2);
        __builtin_amdgcn_fence(__ATOMIC_ACQUIRE, "agent");
    }
    __syncthreads();
}

// ---------------------------------------------------------------------------
// Persistent decoder loop v5 — r6 structure (f32 everywhere in-loop, 2 phases,
// 2 barriers/step), latency-chain fixes:
//  * phase A staging: float4 loads, 32-k chunks, 8 dbuf rounds (was 16)
//  * scores: float4 reads of hs (LDS) and keys (global), 4x fewer load instrs
//  * ctx: float2 + unroll for ILP across the 50-s chain
//  * gate zp-reduce fully unrolled (32 independent loads in flight)
// grid = 256 x 512. Block beta holds Wcomb slice (ks=beta>>5, nt=beta&31).
// ---------------------------------------------------------------------------
__global__ __launch_bounds__(512) void decoder_loop5(
    const float* __restrict__ zemb,   // [3200][4096] (in d_out)
    const float* __restrict__ Wcomb,  // [2048][4096]
    const float* __restrict__ keys,   // [64][50][1024]
    const float* __restrict__ memory, // [64][50][1024]
    const float* __restrict__ c0,
    float* __restrict__ hcprev,       // [64][2048]
    float* __restrict__ zp,           // [8][64][4096]
    float* __restrict__ hc_all,       // [64][50][2048]
    unsigned* bar)
{
    __shared__ float Bw[256 * 128];   // 128 KB persistent Wcomb slice
    __shared__ float As[2][32][68];   // 17.4 KB double-buffered A staging
    __shared__ float hs[1024];
    __shared__ float sc[64];
    __shared__ float al[64];

    const int beta = blockIdx.x;
    const int tid  = threadIdx.x;
    unsigned gen = 0;

    const int nt = beta & 31, ks = beta >> 5;
    const int koff = ks * 256;
    const int c0c  = nt * 128;

    // ---- load persistent Wcomb slice into LDS (once) ----
    {
        const int k_sub = tid >> 5;          // 0..15
        const int c4    = (tid & 31) * 4;    // 0..124
#pragma unroll
        for (int it = 0; it < 16; ++it) {
            int k = it * 16 + k_sub;
            *(float4*)&Bw[k * 128 + c4] =
                *(const float4*)&Wcomb[(size_t)(koff + k) * U4_ + c0c + c4];
        }
    }

    // ---- c-state in registers of blocks 0..63 ----
    const int b = beta;
    float creg[2] = {0.f, 0.f};
    if (beta < 64) {
        creg[0] = c0[b * U_ + tid];
        creg[1] = c0[b * U_ + tid + 512];
    }
    __syncthreads();
    // No pre-loop grid barrier needed: t=0 reads only pre-loop kernel outputs
    // (zp from zgemm_partial, zemb, keys), visible via kernel-boundary sync.

    // phase-A indices: 4x4 micro-tile, 64x32 staging chunks (float4/thread)
    const int tx   = tid & 31;
    const int ty   = tid >> 5;           // 0..15
    const int srow = tid >> 3;           // 0..63
    const int sk4  = (tid & 7) * 4;      // 0,4,..,28

    for (int t = 0; t < T_; ++t) {
        const int KS = t ? 8 : 4;

        // ---------------- phase A (t>=1): z partials from LDS weights -------
        if (t) {
            float acc[4][4];
#pragma unroll
            for (int i = 0; i < 4; ++i)
#pragma unroll
                for (int j = 0; j < 4; ++j) acc[i][j] = 0.f;

            const float* ap = &hcprev[srow * 2048 + koff];
            float4 r1;
            {
                float4 r0 = *(const float4*)&ap[sk4];
                As[0][sk4 + 0][srow] = r0.x;
                As[0][sk4 + 1][srow] = r0.y;
                As[0][sk4 + 2][srow] = r0.z;
                As[0][sk4 + 3][srow] = r0.w;
                r1 = *(const float4*)&ap[32 + sk4];
            }
            __syncthreads();

            for (int kc = 0; kc < 8; ++kc) {
                const int cur = kc & 1;
                const float* bwp = &Bw[(kc * 32) * 128];
#pragma unroll
                for (int kk = 0; kk < 32; ++kk) {
                    float4 af = *(const float4*)&As[cur][kk][ty * 4];
                    float4 bf = *(const float4*)&bwp[kk * 128 + tx * 4];
                    float a_[4] = {af.x, af.y, af.z, af.w};
                    float b_[4] = {bf.x, bf.y, bf.z, bf.w};
#pragma unroll
                    for (int i = 0; i < 4; ++i)
#pragma unroll
                        for (int j = 0; j < 4; ++j)
                            acc[i][j] = fmaf(a_[i], b_[j], acc[i][j]);
                }
                if (kc < 7) {
                    As[cur ^ 1][sk4 + 0][srow] = r1.x;
                    As[cur ^ 1][sk4 + 1][srow] = r1.y;
                    As[cur ^ 1][sk4 + 2][srow] = r1.z;
                    As[cur ^ 1][sk4 + 3][srow] = r1.w;
                    if (kc < 6)
                        r1 = *(const float4*)&ap[(kc + 2) * 32 + sk4];
                }
                __syncthreads();
            }
#pragma unroll
            for (int i = 0; i < 4; ++i) {
                int m = ty * 4 + i;
                *(float4*)&zp[((size_t)ks * 64 + m) * U4_ + c0c + tx * 4] =
                    make_float4(acc[i][0], acc[i][1], acc[i][2], acc[i][3]);
            }
            gbar(bar, gen);
        }

        // ---------------- phase BC: gates + attention (blocks < 64) ---------
        if (beta < 64) {
            const float* ze = &zemb[((size_t)b * T_ + t) * U4_];
            float hn_[2];
#pragma unroll
            for (int i = 0; i < 2; ++i) {
                const int u = tid + 512 * i;
                float zg[4];
#pragma unroll
                for (int g = 0; g < 4; ++g) {
                    const int col = g * U_ + u;
                    float a = ze[col];
#pragma unroll
                    for (int s = 0; s < 8; ++s)
                        if (s < KS) a += zp[((size_t)s * 64 + b) * U4_ + col];
                    zg[g] = a;
                }
                const float si = 1.f / (1.f + expf(-zg[0]));
                const float sf = 1.f / (1.f + expf(-zg[1]));
                const float tg = tanhf(zg[2]);
                const float so = 1.f / (1.f + expf(-zg[3]));
                const float cn = sf * creg[i] + si * tg;
                creg[i] = cn;
                const float hn = so * tanhf(cn);
                hn_[i] = hn;
                hs[u] = hn;
            }
            __syncthreads();
#pragma unroll
            for (int i = 0; i < 2; ++i) {
                const int u = tid + 512 * i;
                hcprev[b * 2048 + u] = hn_[i];
                hc_all[((size_t)b * T_ + t) * 2048 + u] = hn_[i];
            }

            // scores: 8 waves; per (wave,s): lane covers u = lane*16..+15
            const int lane = tid & 63, w = tid >> 6;
            for (int s = w; s < S_; s += 8) {
                const float* kp = &keys[((size_t)b * S_ + s) * U_ + lane * 16];
                const float* hp = &hs[lane * 16];
                float p = 0.f;
#pragma unroll
                for (int q = 0; q < 4; ++q) {
                    float4 kv = *(const float4*)&kp[q * 4];
                    float4 hv = *(const float4*)&hp[q * 4];
                    p = fmaf(hv.x, kv.x, p);
                    p = fmaf(hv.y, kv.y, p);
                    p = fmaf(hv.z, kv.z, p);
                    p = fmaf(hv.w, kv.w, p);
                }
#pragma unroll
                for (int off = 32; off > 0; off >>= 1)
                    p += __shfl_xor(p, off);
                if (lane == 0) sc[s] = p;
            }
            __syncthreads();

            if (tid < 64) {
                float v = (tid < S_) ? sc[tid] : -INFINITY;
                float m = v;
#pragma unroll
                for (int off = 32; off > 0; off >>= 1)
                    m = fmaxf(m, __shfl_xor(m, off));
                float e = (tid < S_) ? expf(v - m) : 0.f;
                float ssum = e;
#pragma unroll
                for (int off = 32; off > 0; off >>= 1)
                    ssum += __shfl_xor(ssum, off);
                if (tid < S_) al[tid] = e / ssum;
            }
            __syncthreads();

            // ctx: thread owns u = 2*tid, 2*tid+1 (float2), unrolled s-chain
            {
                const float2* mp = (const float2*)&memory[(size_t)b * S_ * U_];
                float cx = 0.f, cy = 0.f;
#pragma unroll 10
                for (int s = 0; s < S_; ++s) {
                    float2 mv = mp[s * 512 + tid];
                    const float a = al[s];
                    cx = fmaf(a, mv.x, cx);
                    cy = fmaf(a, mv.y, cy);
                }
                float2 cv = make_float2(cx, cy);
                *(float2*)&hcprev[b * 2048 + U_ + tid * 2] = cv;
                *(float2*)&hc_all[((size_t)b * T_ + t) * 2048 + U_ + tid * 2] = cv;
            }
        }
        gbar(bar, gen);
    }
}

// ---------------------------------------------------------------------------
// bf16 MFMA GEMM: C[3200][V] = A[3200][1024] @ B[1024][VP_] + bias.
// ---------------------------------------------------------------------------
__global__ __launch_bounds__(256) void gemm_wo_mfma(
    const bf16_t* __restrict__ A,
    const bf16_t* __restrict__ Bw,
    const float*  __restrict__ bias,
    float* __restrict__ C)
{
    __shared__ bf16_t As[128][40];
    __shared__ bf16_t Bs[128][40];

    const int n0  = blockIdx.x * 128;
    const int m0  = blockIdx.y * 128;
    const int tid = threadIdx.x;
    const int wave = tid >> 6, lane = tid & 63;
    const int wr = wave >> 1, wc = wave & 1;
    const int lr = lane & 15;
    const int lk = lane >> 4;

    f32x4 acc[4][4] = {};

    const int ar = tid >> 1;
    const int ak = (tid & 1) * 16;
    const int bk = tid >> 3;
    const int bn = (tid & 7) * 16;

    for (int k0 = 0; k0 < U_; k0 += 32) {
        {
            const bf16_t* ap = &A[(size_t)(m0 + ar) * U_ + k0 + ak];
            *(bf16x8*)&As[ar][ak]     = *(const bf16x8*)ap;
            *(bf16x8*)&As[ar][ak + 8] = *(const bf16x8*)(ap + 8);
        }
        {
            const bf16_t* bp = &Bw[(size_t)(k0 + bk) * VP_ + n0 + bn];
            bf16x8 v0 = *(const bf16x8*)bp;
            bf16x8 v1 = *(const bf16x8*)(bp + 8);
#pragma unroll
            for (int i = 0; i < 8; ++i) Bs[bn + i][bk] = v0[i];
#pragma unroll
            for (int i = 0; i < 8; ++i) Bs[bn + 8 + i][bk] = v1[i];
        }
        __syncthreads();

        bf16x8 af[4], bf[4];
#pragma unroll
        for (int m = 0; m < 4; ++m)
            af[m] = *(const bf16x8*)&As[wr * 64 + m * 16 + lr][lk * 8];
#pragma unroll
        for (int n = 0; n < 4; ++n)
            bf[n] = *(const bf16x8*)&Bs[wc * 64 + n * 16 + lr][lk * 8];
#pragma unroll
        for (int m = 0; m < 4; ++m)
#pragma unroll
            for (int n = 0; n < 4; ++n)
                acc[m][n] = __builtin_amdgcn_mfma_f32_16x16x32_bf16(
                    af[m], bf[n], acc[m][n], 0, 0, 0);
        __syncthreads();
    }

#pragma unroll
    for (int m = 0; m < 4; ++m) {
        const int row = m0 + wr * 64 + m * 16 + lk * 4;
#pragma unroll
        for (int n = 0; n < 4; ++n) {
            const int col = n0 + wc * 64 + n * 16 + lr;
            if (col < V_) {
                const float bb = bias[col];
#pragma unroll
                for (int r = 0; r < 4; ++r)
                    C[(size_t)(row + r) * V_ + col] = acc[m][n][r] + bb;
            }
        }
    }
}

// ---------------------------------------------------------------------------
extern "C" void kernel_launch(void* const* d_in, const int* in_sizes, int n_in,
                              void* d_out, int out_size, void* d_ws, size_t ws_size,
                              hipStream_t stream)
{
    const int*   tokens = (const int*)  d_in[0];
    const float* memory = (const float*)d_in[1];
    const float* h0     = (const float*)d_in[2];
    const float* c0     = (const float*)d_in[3];
    const float* emb    = (const float*)d_in[4];
    const float* Wx     = (const float*)d_in[5];
    const float* Uh     = (const float*)d_in[6];
    const float* bvec   = (const float*)d_in[7];
    const float* Wm     = (const float*)d_in[8];
    const float* Wa     = (const float*)d_in[9];
    const float* Wo     = (const float*)d_in[10];
    const float* bo     = (const float*)d_in[11];
    float* out = (float*)d_out;

    // ---- workspace layout (float units) ----
    float* ws = (float*)d_ws;
    size_t off = 0;
    float*   Wcomb  = ws + off; off += (size_t)2048 * U4_;      // 33.55 MB
    float*   keys   = ws + off; off += (size_t)B_ * S_ * U_;    // 13.11 MB
    float*   hc_all = ws + off; off += (size_t)B_ * T_ * 2048;  // 26.21 MB
    float*   zp     = ws + off; off += (size_t)8 * B_ * U4_;    //  8.39 MB
    float*   hcprev = ws + off; off += (size_t)B_ * 2048;       //  0.52 MB
    float*   x_emb  = ws + off; off += (size_t)B_ * T_ * E_;    //  1.28 MB
    unsigned* bar   = (unsigned*)(ws + off); off += 64;
    bf16_t*  wo_bf  = (bf16_t*)(ws + off); off += (size_t)1024 * VP_ / 2; // 61.6 MB
    const size_t need_bytes = off * sizeof(float);

    // d_out-resident scratch (dead before the final GEMM writes out)
    float* zemb = out;                             // [3200][4096] 52.4 MB
    // post-loop aliases (Wcomb dead after the loop)
    float*  attn_all = Wcomb;                      // 13.1 MB <= 33.5 MB
    bf16_t* abf      = (bf16_t*)(Wcomb + (size_t)B_ * T_ * U_);

    const bool use_mfma = (ws_size >= need_bytes);

    (void)hipMemsetAsync(bar, 0, sizeof(unsigned), stream);

    // ---- pre-loop ----
    gather_emb<<<B_ * T_, 128, 0, stream>>>(tokens, emb, x_emb);
    // zemb = x_emb @ Wx[0:100] + b
    gemm128<<<dim3(32, 25), 256, 0, stream>>>(
        x_emb, E_, Wx, U4_, zemb, U4_, U4_, E_, bvec);
    // Wcomb = Wa @ Wx[100:1124]
    gemm128<<<dim3(32, 16), 256, 0, stream>>>(
        Wa, U_, Wx + (size_t)E_ * U4_, U4_, Wcomb, U4_, U4_, U_, nullptr);
    // Wcomb[0:1024] += Uh
    add_inplace<<<(1024 * U4_) / 256, 256, 0, stream>>>(Wcomb, Uh, 1024 * U4_);
    // keys = memory @ Wm
    gemm128<<<dim3(8, 25), 256, 0, stream>>>(
        memory, U_, Wm, U_, keys, U_, U_, U_, nullptr);
    // t=0 z-partials: zp[0..3] = h0 @ Uh  (KS=4)
    zgemm_partial<<<dim3(64, 4), 256, 0, stream>>>(h0, U_, Uh, zp);
    // Wo -> bf16 padded (terminal GEMM only; safe — error not amplified)
    if (use_mfma)
        cast_wo_bf16<<<dim3((VP_ + 255) / 256, 1024), 256, 0, stream>>>(Wo, wo_bf);

    // ---- persistent recurrent loop (all-f32 in-loop data) ----
    decoder_loop5<<<256, 512, 0, stream>>>(
        zemb, Wcomb, keys, memory, c0, hcprev, zp, hc_all, bar);

    // ---- post-loop ----
    // attn_all = hc_all @ Wa   (M=3200, N=1024, K=2048) [into dead Wcomb]
    gemm128<<<dim3(8, 25), 256, 0, stream>>>(
        hc_all, 2048, Wa, U_, attn_all, U_, U_, 2048, nullptr);

    if (use_mfma) {
        cast_bf16<<<2048, 256, 0, stream>>>(attn_all, abf, B_ * T_ * U_);
        gemm_wo_mfma<<<dim3(VP_ / 128, 25), 256, 0, stream>>>(abf, wo_bf, bo, out);
    } else {
        gemm128<<<dim3(235, 25), 256, 0, stream>>>(
            attn_all, U_, Wo, V_, out, V_, V_, U_, bo);
    }
}

// Round 9
// 6405.078 us; speedup vs baseline: 6.6583x; 1.1125x over previous
//
#include <hip/hip_runtime.h>
#include <math.h>

#define B_  64
#define T_  50
#define S_  50
#define U_  1024
#define E_  100
#define V_  30001
#define U4_ 4096
#define VP_ 30080   // V padded to a multiple of 128 for bf16 staging alignment

typedef __bf16 bf16_t;
typedef bf16_t bf16x8 __attribute__((ext_vector_type(8)));
typedef float  f32x4  __attribute__((ext_vector_type(4)));

// ---------------------------------------------------------------------------
// Generic tiled f32 GEMM: C[M,N] = A[M,K] @ B[K,N] (+ bias).
// BM=BN=128, BK=8, 256 threads, 8x8 micro-tile. M%128==0 required.
// ---------------------------------------------------------------------------
__global__ __launch_bounds__(256) void gemm128(
    const float* __restrict__ A, int lda,
    const float* __restrict__ Bm, int ldb,
    float* __restrict__ C, int ldc,
    int N, int K, const float* __restrict__ bias)
{
    __shared__ float As[8][132];
    __shared__ float Bs[8][132];

    const int n0  = blockIdx.x * 128;
    const int m0  = blockIdx.y * 128;
    const int tid = threadIdx.x;
    const int tx  = tid & 15, ty = tid >> 4;

    float acc[8][8];
#pragma unroll
    for (int i = 0; i < 8; ++i)
#pragma unroll
        for (int j = 0; j < 8; ++j) acc[i][j] = 0.f;

    const int ra = tid >> 1, ca = (tid & 1) * 4;
    const int rb = tid >> 5, cb = (tid & 31) * 4;
    const bool fast_b = ((ldb & 3) == 0) && (n0 + 128 <= N);

    for (int k0 = 0; k0 < K; k0 += 8) {
        const float* ap = &A[(size_t)(m0 + ra) * lda + k0 + ca];
        float4 av;
        if (k0 + 8 <= K) {
            av = *(const float4*)ap;
        } else {
            av.x = (k0 + ca + 0 < K) ? ap[0] : 0.f;
            av.y = (k0 + ca + 1 < K) ? ap[1] : 0.f;
            av.z = (k0 + ca + 2 < K) ? ap[2] : 0.f;
            av.w = (k0 + ca + 3 < K) ? ap[3] : 0.f;
        }
        As[ca + 0][ra] = av.x;
        As[ca + 1][ra] = av.y;
        As[ca + 2][ra] = av.z;
        As[ca + 3][ra] = av.w;

        float4 bv = make_float4(0.f, 0.f, 0.f, 0.f);
        if (k0 + rb < K) {
            const float* bp = &Bm[(size_t)(k0 + rb) * ldb];
            if (fast_b) {
                bv = *(const float4*)&bp[n0 + cb];
            } else {
                bv.x = (n0 + cb + 0 < N) ? bp[n0 + cb + 0] : 0.f;
                bv.y = (n0 + cb + 1 < N) ? bp[n0 + cb + 1] : 0.f;
                bv.z = (n0 + cb + 2 < N) ? bp[n0 + cb + 2] : 0.f;
                bv.w = (n0 + cb + 3 < N) ? bp[n0 + cb + 3] : 0.f;
            }
        }
        *(float4*)&Bs[rb][cb] = bv;
        __syncthreads();

#pragma unroll
        for (int kk = 0; kk < 8; ++kk) {
            float4 a0 = *(const float4*)&As[kk][ty * 4];
            float4 a1 = *(const float4*)&As[kk][64 + ty * 4];
            float4 b0 = *(const float4*)&Bs[kk][tx * 4];
            float4 b1 = *(const float4*)&Bs[kk][64 + tx * 4];
            float a_[8] = {a0.x, a0.y, a0.z, a0.w, a1.x, a1.y, a1.z, a1.w};
            float b_[8] = {b0.x, b0.y, b0.z, b0.w, b1.x, b1.y, b1.z, b1.w};
#pragma unroll
            for (int i = 0; i < 8; ++i)
#pragma unroll
                for (int j = 0; j < 8; ++j)
                    acc[i][j] = fmaf(a_[i], b_[j], acc[i][j]);
        }
        __syncthreads();
    }

#pragma unroll
    for (int i = 0; i < 8; ++i) {
        int row = m0 + ((i < 4) ? (ty * 4 + i) : (64 + ty * 4 + (i - 4)));
#pragma unroll
        for (int j = 0; j < 8; ++j) {
            int col = n0 + ((j < 4) ? (tx * 4 + j) : (64 + tx * 4 + (j - 4)));
            if (col < N) {
                float v = acc[i][j];
                if (bias) v += bias[col];
                C[(size_t)row * ldc + col] = v;
            }
        }
    }
}

__global__ void add_inplace(float* __restrict__ dst, const float* __restrict__ src, int n)
{
    int i = blockIdx.x * blockDim.x + threadIdx.x;
    if (i < n) dst[i] += src[i];
}

__global__ void gather_emb(const int* __restrict__ tokens,
                           const float* __restrict__ emb,
                           float* __restrict__ xe)
{
    const int r = blockIdx.x;
    const int e = threadIdx.x;
    if (e < E_) xe[(size_t)r * E_ + e] = emb[(size_t)tokens[r] * E_ + e];
}

__global__ void cast_bf16(const float* __restrict__ src, bf16_t* __restrict__ dst, int n)
{
    int i = blockIdx.x * blockDim.x + threadIdx.x;
    const int stride = gridDim.x * blockDim.x;
    for (; i < n; i += stride) dst[i] = (bf16_t)src[i];
}

// Wo [1024][30001] f32 -> [1024][VP_] bf16, zero-padded tail columns
__global__ void cast_wo_bf16(const float* __restrict__ wo, bf16_t* __restrict__ dst)
{
    const int col = blockIdx.x * 256 + threadIdx.x;
    const int k   = blockIdx.y;
    if (col < VP_)
        dst[(size_t)k * VP_ + col] =
            (col < V_) ? (bf16_t)wo[(size_t)k * V_ + col] : (bf16_t)0.f;
}

// ---------------------------------------------------------------------------
// Split-K GEMM for t=0: zp[(ks*64+b)*4096+n] = sum_{k in slice} h0[b][k]*Uh[k][n]
// ---------------------------------------------------------------------------
__global__ __launch_bounds__(256) void zgemm_partial(
    const float* __restrict__ A, int lda,
    const float* __restrict__ Bm,
    float* __restrict__ zp)
{
    __shared__ float As[64][17];
    __shared__ float Bs[16][68];

    const int n0     = blockIdx.x * 64;
    const int ks     = blockIdx.y;
    const int k_base = ks * 256;
    const int tid    = threadIdx.x;
    const int tx     = tid & 15, ty = tid >> 4;

    float acc[4][4];
#pragma unroll
    for (int i = 0; i < 4; ++i)
#pragma unroll
        for (int j = 0; j < 4; ++j) acc[i][j] = 0.f;

    const int ra = tid >> 2, ca = (tid & 3) * 4;
    const int rb = tid >> 4, cb = (tid & 15) * 4;

    for (int kt = 0; kt < 16; ++kt) {
        const int k0 = k_base + kt * 16;
        float4 av = *(const float4*)&A[(size_t)ra * lda + k0 + ca];
        As[ra][ca + 0] = av.x;
        As[ra][ca + 1] = av.y;
        As[ra][ca + 2] = av.z;
        As[ra][ca + 3] = av.w;
        float4 bv = *(const float4*)&Bm[(size_t)(k0 + rb) * U4_ + n0 + cb];
        *(float4*)&Bs[rb][cb] = bv;
        __syncthreads();
#pragma unroll
        for (int kk = 0; kk < 16; ++kk) {
            float a_[4];
#pragma unroll
            for (int i = 0; i < 4; ++i) a_[i] = As[ty * 4 + i][kk];
            float4 bq = *(const float4*)&Bs[kk][tx * 4];
            float b_[4] = {bq.x, bq.y, bq.z, bq.w};
#pragma unroll
            for (int i = 0; i < 4; ++i)
#pragma unroll
                for (int j = 0; j < 4; ++j)
                    acc[i][j] = fmaf(a_[i], b_[j], acc[i][j]);
        }
        __syncthreads();
    }

#pragma unroll
    for (int i = 0; i < 4; ++i)
        *(float4*)&zp[((size_t)ks * 64 + ty * 4 + i) * U4_ + n0 + tx * 4] =
            make_float4(acc[i][0], acc[i][1], acc[i][2], acc[i][3]);
}

// ---------------------------------------------------------------------------
// Hierarchical grid barrier. Same coherence semantics as the r3/r6-proven
// protocol (release adds flush data to the coherence point before the arrival
// is visible; one acquire fence on exit invalidates L1/L2), but arrival is
// two-level to kill RMW serialization on a single line:
//   level 1: 16 groups x 16 blocks, each group counter on its own 128B line
//   level 2: last arriver of each group adds to the global counter
//   release: everyone polls the global counter (read-only line traffic)
// bars[0] = global counter; bars[32 + g*32] = group g counter.
// ---------------------------------------------------------------------------
__device__ __forceinline__ void gbar(unsigned* bars, unsigned& gen)
{
    __syncthreads();
    if (threadIdx.x == 0) {
        gen++;
        const int g = blockIdx.x & 15;
        unsigned old = __hip_atomic_fetch_add(&bars[32 + g * 32], 1u,
                           __ATOMIC_RELEASE, __HIP_MEMORY_SCOPE_AGENT);
        if (old + 1 == gen * 16u)
            __hip_atomic_fetch_add(&bars[0], 1u,
                           __ATOMIC_RELEASE, __HIP_MEMORY_SCOPE_AGENT);
        while (__hip_atomic_load(&bars[0], __ATOMIC_RELAXED,
                           __HIP_MEMORY_SCOPE_AGENT) < gen * 16u)
            __builtin_amdgcn_s_sleep(4);
        __builtin_amdgcn_fence(__ATOMIC_ACQUIRE, "agent");
    }
    __syncthreads();
}

// ---------------------------------------------------------------------------
// Persistent decoder loop v5 (r8 phase code, unchanged) + hierarchical barrier.
// grid = 256 x 512. Block beta holds Wcomb slice (ks=beta>>5, nt=beta&31).
// ---------------------------------------------------------------------------
__global__ __launch_bounds__(512) void decoder_loop5(
    const float* __restrict__ zemb,   // [3200][4096] (in d_out)
    const float* __restrict__ Wcomb,  // [2048][4096]
    const float* __restrict__ keys,   // [64][50][1024]
    const float* __restrict__ memory, // [64][50][1024]
    const float* __restrict__ c0,
    float* __restrict__ hcprev,       // [64][2048]
    float* __restrict__ zp,           // [8][64][4096]
    float* __restrict__ hc_all,       // [64][50][2048]
    unsigned* bars)
{
    __shared__ float Bw[256 * 128];   // 128 KB persistent Wcomb slice
    __shared__ float As[2][32][68];   // 17.4 KB double-buffered A staging
    __shared__ float hs[1024];
    __shared__ float sc[64];
    __shared__ float al[64];

    const int beta = blockIdx.x;
    const int tid  = threadIdx.x;
    unsigned gen = 0;

    const int nt = beta & 31, ks = beta >> 5;
    const int koff = ks * 256;
    const int c0c  = nt * 128;

    // ---- load persistent Wcomb slice into LDS (once) ----
    {
        const int k_sub = tid >> 5;          // 0..15
        const int c4    = (tid & 31) * 4;    // 0..124
#pragma unroll
        for (int it = 0; it < 16; ++it) {
            int k = it * 16 + k_sub;
            *(float4*)&Bw[k * 128 + c4] =
                *(const float4*)&Wcomb[(size_t)(koff + k) * U4_ + c0c + c4];
        }
    }

    // ---- c-state in registers of blocks 0..63 ----
    const int b = beta;
    float creg[2] = {0.f, 0.f};
    if (beta < 64) {
        creg[0] = c0[b * U_ + tid];
        creg[1] = c0[b * U_ + tid + 512];
    }
    __syncthreads();

    // phase-A indices: 4x4 micro-tile, 64x32 staging chunks (float4/thread)
    const int tx   = tid & 31;
    const int ty   = tid >> 5;           // 0..15
    const int srow = tid >> 3;           // 0..63
    const int sk4  = (tid & 7) * 4;      // 0,4,..,28

    for (int t = 0; t < T_; ++t) {
        const int KS = t ? 8 : 4;

        // ---------------- phase A (t>=1): z partials from LDS weights -------
        if (t) {
            float acc[4][4];
#pragma unroll
            for (int i = 0; i < 4; ++i)
#pragma unroll
                for (int j = 0; j < 4; ++j) acc[i][j] = 0.f;

            const float* ap = &hcprev[srow * 2048 + koff];
            float4 r1;
            {
                float4 r0 = *(const float4*)&ap[sk4];
                As[0][sk4 + 0][srow] = r0.x;
                As[0][sk4 + 1][srow] = r0.y;
                As[0][sk4 + 2][srow] = r0.z;
                As[0][sk4 + 3][srow] = r0.w;
                r1 = *(const float4*)&ap[32 + sk4];
            }
            __syncthreads();

            for (int kc = 0; kc < 8; ++kc) {
                const int cur = kc & 1;
                const float* bwp = &Bw[(kc * 32) * 128];
#pragma unroll
                for (int kk = 0; kk < 32; ++kk) {
                    float4 af = *(const float4*)&As[cur][kk][ty * 4];
                    float4 bf = *(const float4*)&bwp[kk * 128 + tx * 4];
                    float a_[4] = {af.x, af.y, af.z, af.w};
                    float b_[4] = {bf.x, bf.y, bf.z, bf.w};
#pragma unroll
                    for (int i = 0; i < 4; ++i)
#pragma unroll
                        for (int j = 0; j < 4; ++j)
                            acc[i][j] = fmaf(a_[i], b_[j], acc[i][j]);
                }
                if (kc < 7) {
                    As[cur ^ 1][sk4 + 0][srow] = r1.x;
                    As[cur ^ 1][sk4 + 1][srow] = r1.y;
                    As[cur ^ 1][sk4 + 2][srow] = r1.z;
                    As[cur ^ 1][sk4 + 3][srow] = r1.w;
                    if (kc < 6)
                        r1 = *(const float4*)&ap[(kc + 2) * 32 + sk4];
                }
                __syncthreads();
            }
#pragma unroll
            for (int i = 0; i < 4; ++i) {
                int m = ty * 4 + i;
                *(float4*)&zp[((size_t)ks * 64 + m) * U4_ + c0c + tx * 4] =
                    make_float4(acc[i][0], acc[i][1], acc[i][2], acc[i][3]);
            }
            gbar(bars, gen);
        }

        // ---------------- phase BC: gates + attention (blocks < 64) ---------
        if (beta < 64) {
            const float* ze = &zemb[((size_t)b * T_ + t) * U4_];
            float hn_[2];
#pragma unroll
            for (int i = 0; i < 2; ++i) {
                const int u = tid + 512 * i;
                float zg[4];
#pragma unroll
                for (int g = 0; g < 4; ++g) {
                    const int col = g * U_ + u;
                    float a = ze[col];
#pragma unroll
                    for (int s = 0; s < 8; ++s)
                        if (s < KS) a += zp[((size_t)s * 64 + b) * U4_ + col];
                    zg[g] = a;
                }
                const float si = 1.f / (1.f + expf(-zg[0]));
                const float sf = 1.f / (1.f + expf(-zg[1]));
                const float tg = tanhf(zg[2]);
                const float so = 1.f / (1.f + expf(-zg[3]));
                const float cn = sf * creg[i] + si * tg;
                creg[i] = cn;
                const float hn = so * tanhf(cn);
                hn_[i] = hn;
                hs[u] = hn;
            }
            __syncthreads();
#pragma unroll
            for (int i = 0; i < 2; ++i) {
                const int u = tid + 512 * i;
                hcprev[b * 2048 + u] = hn_[i];
                hc_all[((size_t)b * T_ + t) * 2048 + u] = hn_[i];
            }

            // scores: 8 waves; per (wave,s): lane covers u = lane*16..+15
            const int lane = tid & 63, w = tid >> 6;
            for (int s = w; s < S_; s += 8) {
                const float* kp = &keys[((size_t)b * S_ + s) * U_ + lane * 16];
                const float* hp = &hs[lane * 16];
                float p = 0.f;
#pragma unroll
                for (int q = 0; q < 4; ++q) {
                    float4 kv = *(const float4*)&kp[q * 4];
                    float4 hv = *(const float4*)&hp[q * 4];
                    p = fmaf(hv.x, kv.x, p);
                    p = fmaf(hv.y, kv.y, p);
                    p = fmaf(hv.z, kv.z, p);
                    p = fmaf(hv.w, kv.w, p);
                }
#pragma unroll
                for (int off = 32; off > 0; off >>= 1)
                    p += __shfl_xor(p, off);
                if (lane == 0) sc[s] = p;
            }
            __syncthreads();

            if (tid < 64) {
                float v = (tid < S_) ? sc[tid] : -INFINITY;
                float m = v;
#pragma unroll
                for (int off = 32; off > 0; off >>= 1)
                    m = fmaxf(m, __shfl_xor(m, off));
                float e = (tid < S_) ? expf(v - m) : 0.f;
                float ssum = e;
#pragma unroll
                for (int off = 32; off > 0; off >>= 1)
                    ssum += __shfl_xor(ssum, off);
                if (tid < S_) al[tid] = e / ssum;
            }
            __syncthreads();

            // ctx: thread owns u = 2*tid, 2*tid+1 (float2), unrolled s-chain
            {
                const float2* mp = (const float2*)&memory[(size_t)b * S_ * U_];
                float cx = 0.f, cy = 0.f;
#pragma unroll 10
                for (int s = 0; s < S_; ++s) {
                    float2 mv = mp[s * 512 + tid];
                    const float a = al[s];
                    cx = fmaf(a, mv.x, cx);
                    cy = fmaf(a, mv.y, cy);
                }
                float2 cv = make_float2(cx, cy);
                *(float2*)&hcprev[b * 2048 + U_ + tid * 2] = cv;
                *(float2*)&hc_all[((size_t)b * T_ + t) * 2048 + U_ + tid * 2] = cv;
            }
        }
        gbar(bars, gen);
    }
}

// ---------------------------------------------------------------------------
// bf16 MFMA GEMM: C[3200][V] = A[3200][1024] @ B[1024][VP_] + bias.
// ---------------------------------------------------------------------------
__global__ __launch_bounds__(256) void gemm_wo_mfma(
    const bf16_t* __restrict__ A,
    const bf16_t* __restrict__ Bw,
    const float*  __restrict__ bias,
    float* __restrict__ C)
{
    __shared__ bf16_t As[128][40];
    __shared__ bf16_t Bs[128][40];

    const int n0  = blockIdx.x * 128;
    const int m0  = blockIdx.y * 128;
    const int tid = threadIdx.x;
    const int wave = tid >> 6, lane = tid & 63;
    const int wr = wave >> 1, wc = wave & 1;
    const int lr = lane & 15;
    const int lk = lane >> 4;

    f32x4 acc[4][4] = {};

    const int ar = tid >> 1;
    const int ak = (tid & 1) * 16;
    const int bk = tid >> 3;
    const int bn = (tid & 7) * 16;

    for (int k0 = 0; k0 < U_; k0 += 32) {
        {
            const bf16_t* ap = &A[(size_t)(m0 + ar) * U_ + k0 + ak];
            *(bf16x8*)&As[ar][ak]     = *(const bf16x8*)ap;
            *(bf16x8*)&As[ar][ak + 8] = *(const bf16x8*)(ap + 8);
        }
        {
            const bf16_t* bp = &Bw[(size_t)(k0 + bk) * VP_ + n0 + bn];
            bf16x8 v0 = *(const bf16x8*)bp;
            bf16x8 v1 = *(const bf16x8*)(bp + 8);
#pragma unroll
            for (int i = 0; i < 8; ++i) Bs[bn + i][bk] = v0[i];
#pragma unroll
            for (int i = 0; i < 8; ++i) Bs[bn + 8 + i][bk] = v1[i];
        }
        __syncthreads();

        bf16x8 af[4], bf[4];
#pragma unroll
        for (int m = 0; m < 4; ++m)
            af[m] = *(const bf16x8*)&As[wr * 64 + m * 16 + lr][lk * 8];
#pragma unroll
        for (int n = 0; n < 4; ++n)
            bf[n] = *(const bf16x8*)&Bs[wc * 64 + n * 16 + lr][lk * 8];
#pragma unroll
        for (int m = 0; m < 4; ++m)
#pragma unroll
            for (int n = 0; n < 4; ++n)
                acc[m][n] = __builtin_amdgcn_mfma_f32_16x16x32_bf16(
                    af[m], bf[n], acc[m][n], 0, 0, 0);
        __syncthreads();
    }

#pragma unroll
    for (int m = 0; m < 4; ++m) {
        const int row = m0 + wr * 64 + m * 16 + lk * 4;
#pragma unroll
        for (int n = 0; n < 4; ++n) {
            const int col = n0 + wc * 64 + n * 16 + lr;
            if (col < V_) {
                const float bb = bias[col];
#pragma unroll
                for (int r = 0; r < 4; ++r)
                    C[(size_t)(row + r) * V_ + col] = acc[m][n][r] + bb;
            }
        }
    }
}

// ---------------------------------------------------------------------------
extern "C" void kernel_launch(void* const* d_in, const int* in_sizes, int n_in,
                              void* d_out, int out_size, void* d_ws, size_t ws_size,
                              hipStream_t stream)
{
    const int*   tokens = (const int*)  d_in[0];
    const float* memory = (const float*)d_in[1];
    const float* h0     = (const float*)d_in[2];
    const float* c0     = (const float*)d_in[3];
    const float* emb    = (const float*)d_in[4];
    const float* Wx     = (const float*)d_in[5];
    const float* Uh     = (const float*)d_in[6];
    const float* bvec   = (const float*)d_in[7];
    const float* Wm     = (const float*)d_in[8];
    const float* Wa     = (const float*)d_in[9];
    const float* Wo     = (const float*)d_in[10];
    const float* bo     = (const float*)d_in[11];
    float* out = (float*)d_out;

    // ---- workspace layout (float units) ----
    float* ws = (float*)d_ws;
    size_t off = 0;
    float*   Wcomb  = ws + off; off += (size_t)2048 * U4_;      // 33.55 MB
    float*   keys   = ws + off; off += (size_t)B_ * S_ * U_;    // 13.11 MB
    float*   hc_all = ws + off; off += (size_t)B_ * T_ * 2048;  // 26.21 MB
    float*   zp     = ws + off; off += (size_t)8 * B_ * U4_;    //  8.39 MB
    float*   hcprev = ws + off; off += (size_t)B_ * 2048;       //  0.52 MB
    float*   x_emb  = ws + off; off += (size_t)B_ * T_ * E_;    //  1.28 MB
    unsigned* bars  = (unsigned*)(ws + off); off += 1024;       //  4 KB
    bf16_t*  wo_bf  = (bf16_t*)(ws + off); off += (size_t)1024 * VP_ / 2; // 61.6 MB
    const size_t need_bytes = off * sizeof(float);

    // d_out-resident scratch (dead before the final GEMM writes out)
    float* zemb = out;                             // [3200][4096] 52.4 MB
    // post-loop aliases (Wcomb dead after the loop)
    float*  attn_all = Wcomb;                      // 13.1 MB <= 33.5 MB
    bf16_t* abf      = (bf16_t*)(Wcomb + (size_t)B_ * T_ * U_);

    const bool use_mfma = (ws_size >= need_bytes);

    (void)hipMemsetAsync(bars, 0, 1024 * sizeof(unsigned), stream);

    // ---- pre-loop ----
    gather_emb<<<B_ * T_, 128, 0, stream>>>(tokens, emb, x_emb);
    // zemb = x_emb @ Wx[0:100] + b
    gemm128<<<dim3(32, 25), 256, 0, stream>>>(
        x_emb, E_, Wx, U4_, zemb, U4_, U4_, E_, bvec);
    // Wcomb = Wa @ Wx[100:1124]
    gemm128<<<dim3(32, 16), 256, 0, stream>>>(
        Wa, U_, Wx + (size_t)E_ * U4_, U4_, Wcomb, U4_, U4_, U_, nullptr);
    // Wcomb[0:1024] += Uh
    add_inplace<<<(1024 * U4_) / 256, 256, 0, stream>>>(Wcomb, Uh, 1024 * U4_);
    // keys = memory @ Wm
    gemm128<<<dim3(8, 25), 256, 0, stream>>>(
        memory, U_, Wm, U_, keys, U_, U_, U_, nullptr);
    // t=0 z-partials: zp[0..3] = h0 @ Uh  (KS=4)
    zgemm_partial<<<dim3(64, 4), 256, 0, stream>>>(h0, U_, Uh, zp);
    // Wo -> bf16 padded (terminal GEMM only; safe — error not amplified)
    if (use_mfma)
        cast_wo_bf16<<<dim3((VP_ + 255) / 256, 1024), 256, 0, stream>>>(Wo, wo_bf);

    // ---- persistent recurrent loop (all-f32 in-loop data) ----
    decoder_loop5<<<256, 512, 0, stream>>>(
        zemb, Wcomb, keys, memory, c0, hcprev, zp, hc_all, bars);

    // ---- post-loop ----
    // attn_all = hc_all @ Wa   (M=3200, N=1024, K=2048) [into dead Wcomb]
    gemm128<<<dim3(8, 25), 256, 0, stream>>>(
        hc_all, 2048, Wa, U_, attn_all, U_, U_, 2048, nullptr);

    if (use_mfma) {
        cast_bf16<<<2048, 256, 0, stream>>>(attn_all, abf, B_ * T_ * U_);
        gemm_wo_mfma<<<dim3(VP_ / 128, 25), 256, 0, stream>>>(abf, wo_bf, bo, out);
    } else {
        gemm128<<<dim3(235, 25), 256, 0, stream>>>(
            attn_all, U_, Wo, V_, out, V_, V_, U_, bo);
    }
}